// Round 8
// baseline (481.859 us; speedup 1.0000x reference)
//
#include <hip/hip_runtime.h>

typedef unsigned short ushort_t;
typedef unsigned int uint32;
typedef __attribute__((ext_vector_type(4))) float f32x4;
typedef __attribute__((ext_vector_type(16))) float f32x16;
typedef __attribute__((ext_vector_type(8))) short bf16x8;

#define B_   4
#define S_   2048
#define D_   1024
#define H_   16
#define HD_  64
#define DFF_ 4096
#define M_   (B_ * S_)          // 8192 rows (tokens)

#define RES_   0.28867513459481287f   // 1/sqrt(12)
#define SCALE_ 0.03125f               // 1/sqrt(1024)
#define EPS_   1e-5f
#define LOG2E_ 1.4426950408889634f

__device__ __forceinline__ ushort_t f2bf(float f) {
    union { float f; uint32 u; } c; c.f = f;
    uint32 u = c.u + 0x7fffu + ((c.u >> 16) & 1u);
    return (ushort_t)(u >> 16);
}
__device__ __forceinline__ float bf2f(ushort_t h) {
    union { uint32 u; float f; } c; c.u = ((uint32)h) << 16;
    return c.f;
}
__device__ __forceinline__ float fexp2(float x) {
    float r; asm("v_exp_f32 %0, %1" : "=v"(r) : "v"(x)); return r;
}
__device__ __forceinline__ uint32 cvt_pk_bf16(float lo, float hi) {
    uint32 r;
    asm("v_cvt_pk_bf16_f32 %0, %1, %2" : "=v"(r) : "v"(lo), "v"(hi));
    return r;
}

#define GLDS(src_, dst_)                                                     \
    __builtin_amdgcn_global_load_lds(                                        \
        (const __attribute__((address_space(1))) void*)(src_),               \
        (__attribute__((address_space(3))) void*)(dst_), 16, 0, 0)

// ---------------------------------------------------------------------------
// Transpose + fp32->bf16 cast:  W[K][N] (fp32, row-major) -> Wt[N][K] (bf16)
// ---------------------------------------------------------------------------
__global__ __launch_bounds__(256) void transpose_cast_kernel(
    const float* __restrict__ W, ushort_t* __restrict__ Wt, int K, int N)
{
    __shared__ float tile[32][33];
    const int bx = blockIdx.x * 32;  // N offset
    const int by = blockIdx.y * 32;  // K offset
    const int tx = threadIdx.x;      // 0..31
    const int ty = threadIdx.y;      // 0..7
    #pragma unroll
    for (int i = 0; i < 32; i += 8)
        tile[ty + i][tx] = W[(size_t)(by + ty + i) * N + bx + tx];
    __syncthreads();
    #pragma unroll
    for (int i = 0; i < 32; i += 8)
        Wt[(size_t)(bx + ty + i) * K + by + tx] = f2bf(tile[tx][ty + i]);
}

// ---------------------------------------------------------------------------
// Concat bq,bk,bv -> bqkv[3072]
// ---------------------------------------------------------------------------
__global__ void concat_bias_kernel(const float* __restrict__ bq,
                                   const float* __restrict__ bk,
                                   const float* __restrict__ bv,
                                   float* __restrict__ bqkv)
{
    int i = blockIdx.x * blockDim.x + threadIdx.x;
    if (i < 3 * D_) {
        float v = (i < D_) ? bq[i] : (i < 2 * D_) ? bk[i - D_] : bv[i - 2 * D_];
        bqkv[i] = v;
    }
}

// ---------------------------------------------------------------------------
// LayerNorm: fp32 in [rows][1024] -> bf16 out
// ---------------------------------------------------------------------------
__global__ __launch_bounds__(256) void ln_kernel(
    const float* __restrict__ x, const float* __restrict__ g,
    const float* __restrict__ be, ushort_t* __restrict__ out)
{
    const int row = blockIdx.x;
    const int t = threadIdx.x;
    const int lane = t & 63;
    const int wave = t >> 6;
    const float4* xr = (const float4*)(x + (size_t)row * D_);
    float4 v = xr[t];
    float s  = v.x + v.y + v.z + v.w;
    float s2 = v.x * v.x + v.y * v.y + v.z * v.z + v.w * v.w;
    #pragma unroll
    for (int off = 32; off; off >>= 1) {
        s  += __shfl_xor(s, off);
        s2 += __shfl_xor(s2, off);
    }
    __shared__ float red[8];
    if (lane == 0) { red[wave * 2] = s; red[wave * 2 + 1] = s2; }
    __syncthreads();
    s  = red[0] + red[2] + red[4] + red[6];
    s2 = red[1] + red[3] + red[5] + red[7];
    const float mean = s * (1.0f / D_);
    const float var  = s2 * (1.0f / D_) - mean * mean;
    const float rstd = rsqrtf(var + EPS_);
    const float4 gv  = ((const float4*)g)[t];
    const float4 bv  = ((const float4*)be)[t];
    ushort_t o[4];
    o[0] = f2bf((v.x - mean) * rstd * gv.x + bv.x);
    o[1] = f2bf((v.y - mean) * rstd * gv.y + bv.y);
    o[2] = f2bf((v.z - mean) * rstd * gv.z + bv.z);
    o[3] = f2bf((v.w - mean) * rstd * gv.w + bv.w);
    *(ushort2*)&out[(size_t)row * D_ + t * 4]     = make_ushort2(o[0], o[1]);
    *(ushort2*)&out[(size_t)row * D_ + t * 4 + 2] = make_ushort2(o[2], o[3]);
}

// ---------------------------------------------------------------------------
// GEMM v5: C[M][N] = epilogue(A[M][K] @ Bt[N][K]^T + bias)
// BM=BN=128, BK=32, 4 waves (wave = 64x64 via 2x2 32x32x16 frags).
// 3-deep LDS rotation (48KB -> 3 blocks/CU, 12 waves), counted vmcnt(4):
// tile t+2's loads stay in flight across the barrier, only t+1's must land.
// T2 swizzle: linear LDS dest + inverse-swizzled GLOBAL src + swizzled reads
// (chunk ^= row&3 over 4 chunks -> 2-way residual = free).
// T1 bijective XCD swizzle (grids % 8 == 0), T5 setprio.
// ---------------------------------------------------------------------------
template <int MODE>
__global__ __launch_bounds__(256, 3) void gemm32_kernel(
    const ushort_t* __restrict__ A, const ushort_t* __restrict__ Bt,
    const float* __restrict__ bias, const float* __restrict__ res,
    void* __restrict__ Cout, int M, int N, int K, int gx)
{
    __shared__ __align__(16) ushort_t As[3][128 * 32];   // 8KB x3
    __shared__ __align__(16) ushort_t Bs[3][128 * 32];   // 8KB x3

    const int tid  = threadIdx.x;
    const int w    = tid >> 6;
    const int lane = tid & 63;
    const int l31  = lane & 31;
    const int g2   = lane >> 5;          // 0/1: k-half within frag
    const int rp   = l31 & 3;            // row parity for read swizzle

    // T1: bijective XCD swizzle (gridDim.x % 8 == 0)
    const int cpx = gridDim.x >> 3;
    const int swz = (blockIdx.x & 7) * cpx + (blockIdx.x >> 3);
    const int bx = swz % gx, by = swz / gx;
    const int m0 = by * 128, n0 = bx * 128;

    const int wm = (w >> 1) * 64;        // 0,64
    const int wn = (w & 1) * 64;         // 0,64

    // staging: A/B = 512 16B-chunks each, 2 per thread.
    // stored chunk (L&3) at row L>>2 holds logical chunk (L&3)^(row&3)
    const ushort_t* srcA[2];
    const ushort_t* srcB[2];
    int ldsA[2], ldsB[2];
    #pragma unroll
    for (int p = 0; p < 2; ++p) {
        const int L = p * 256 + tid;
        const int row = L >> 2;
        srcA[p] = A  + (size_t)(m0 + row) * K + (((L & 3) ^ (row & 3)) << 3);
        srcB[p] = Bt + (size_t)(n0 + row) * K + (((L & 3) ^ (row & 3)) << 3);
        ldsA[p] = (p * 256 + w * 64) * 8;    // wave-uniform; HW adds lane*16B
        ldsB[p] = (p * 256 + w * 64) * 8;
    }

    #define STAGE(t_, buf_)                                                  \
        do {                                                                 \
            GLDS(srcA[0] + (size_t)(t_) * 32, &As[buf_][ldsA[0]]);           \
            GLDS(srcA[1] + (size_t)(t_) * 32, &As[buf_][ldsA[1]]);           \
            GLDS(srcB[0] + (size_t)(t_) * 32, &Bs[buf_][ldsB[0]]);           \
            GLDS(srcB[1] + (size_t)(t_) * 32, &Bs[buf_][ldsB[1]]);           \
        } while (0)

    // frag read: row-major [128][32], logical chunk = kk*2 + g2, stored ^= rp
    #define LDA(mf_, kk_) (*(const bf16x8*)&As[cur][(wm + (mf_) * 32 + l31) * 32 + \
                              ((((kk_) * 2 + g2) ^ rp) << 3)])
    #define LDB(nf_, kk_) (*(const bf16x8*)&Bs[cur][(wn + (nf_) * 32 + l31) * 32 + \
                              ((((kk_) * 2 + g2) ^ rp) << 3)])

    f32x16 acc[2][2] = {};
    const int NT = K >> 5;

    STAGE(0, 0);
    STAGE(1, 1);
    asm volatile("s_waitcnt vmcnt(4)" ::: "memory");   // tile0 landed
    __builtin_amdgcn_s_barrier();

    for (int t = 0; t < NT; ++t) {
        const int cur = t % 3;
        const bool more = (t + 2 < NT);
        if (more) STAGE(t + 2, (t + 2) % 3);

        bf16x8 a0k0 = LDA(0, 0), a1k0 = LDA(1, 0);
        bf16x8 b0k0 = LDB(0, 0), b1k0 = LDB(1, 0);
        bf16x8 a0k1 = LDA(0, 1), a1k1 = LDA(1, 1);
        bf16x8 b0k1 = LDB(0, 1), b1k1 = LDB(1, 1);

        __builtin_amdgcn_s_setprio(1);
        acc[0][0] = __builtin_amdgcn_mfma_f32_32x32x16_bf16(a0k0, b0k0, acc[0][0], 0, 0, 0);
        acc[0][1] = __builtin_amdgcn_mfma_f32_32x32x16_bf16(a0k0, b1k0, acc[0][1], 0, 0, 0);
        acc[1][0] = __builtin_amdgcn_mfma_f32_32x32x16_bf16(a1k0, b0k0, acc[1][0], 0, 0, 0);
        acc[1][1] = __builtin_amdgcn_mfma_f32_32x32x16_bf16(a1k0, b1k0, acc[1][1], 0, 0, 0);
        acc[0][0] = __builtin_amdgcn_mfma_f32_32x32x16_bf16(a0k1, b0k1, acc[0][0], 0, 0, 0);
        acc[0][1] = __builtin_amdgcn_mfma_f32_32x32x16_bf16(a0k1, b1k1, acc[0][1], 0, 0, 0);
        acc[1][0] = __builtin_amdgcn_mfma_f32_32x32x16_bf16(a1k1, b0k1, acc[1][0], 0, 0, 0);
        acc[1][1] = __builtin_amdgcn_mfma_f32_32x32x16_bf16(a1k1, b1k1, acc[1][1], 0, 0, 0);
        __builtin_amdgcn_s_setprio(0);

        if (more)
            asm volatile("s_waitcnt vmcnt(4)" ::: "memory");  // t+1 ready
        else
            asm volatile("s_waitcnt vmcnt(0)" ::: "memory");
        __builtin_amdgcn_s_barrier();
    }
    #undef STAGE
    #undef LDA
    #undef LDB

    // epilogue: 32x32 C/D layout: col = lane&31, row = (r&3) + 8*(r>>2) + 4*g2
    #pragma unroll
    for (int mf = 0; mf < 2; ++mf) {
        #pragma unroll
        for (int nf = 0; nf < 2; ++nf) {
            const int col = n0 + wn + nf * 32 + l31;
            const float bcol = bias[col];
            #pragma unroll
            for (int r = 0; r < 16; ++r) {
                const int row = m0 + wm + mf * 32 + (r & 3) + 8 * (r >> 2) + 4 * g2;
                float v = acc[mf][nf][r] + bcol;
                const size_t idx = (size_t)row * N + col;
                if (MODE == 0) {
                    ((ushort_t*)Cout)[idx] = f2bf(v);
                } else if (MODE == 1) {
                    ((ushort_t*)Cout)[idx] = f2bf(fmaxf(v, 0.0f));
                } else {
                    ((float*)Cout)[idx] = res[idx] + RES_ * v;
                }
            }
        }
    }
}

// ---------------------------------------------------------------------------
// Flash attention v5 (causal) from packed qkv (bf16 [8192][3072]).
// - 64-row q-tiles, 4 waves x 16 rows; paired triangle (uniform 33 iters)
// - swapped QK^T, reg-prefetch staging (T14), exp2 softmax, defer-max (T13)
// out: bf16 [8192][1024]
// ---------------------------------------------------------------------------
__global__ __launch_bounds__(256) void fattn_kernel(
    const ushort_t* __restrict__ qkv, ushort_t* __restrict__ out)
{
    __shared__ __align__(16) ushort_t Ks[64 * 64];     // [key][d], chunk c^=key&7
    __shared__ __align__(16) ushort_t Vt[64 * 64];     // [d][key], chunk c^=(d&7)^((d>>3)&7)
    __shared__ __align__(16) ushort_t Ps[4][16 * 64];  // per-wave [q][key], 16B-chunk c16^=q&7

    const int tid  = threadIdx.x;
    const int lane = tid & 63;
    const int w    = tid >> 6;
    const int bh = blockIdx.y;
    const int b = bh >> 4, h = bh & 15;

    const int l15 = lane & 15;
    const int g   = lane >> 4;

    const size_t rs = 3 * D_;
    const ushort_t* Qg = qkv + (size_t)b * S_ * rs + h * HD_;
    const ushort_t* Kg = Qg + D_;

    // staging geometry (constant per thread)
    const int skey = tid >> 3;          // 0..31 (+32 on pass 1)
    const int sc   = tid & 7;           // 16B chunk within row

    #pragma unroll
    for (int half = 0; half < 2; ++half) {
        const int qt = half ? blockIdx.x : (S_ / 64 - 1) - blockIdx.x;
        const int q0 = qt * 64;
        const int nkb = qt + 1;

        // Q B-frags (col=q=l15, k=g*8+e +kk*32), pre-scaled by SCALE_*log2e
        bf16x8 qf[2];
        {
            const int qrow = q0 + w * 16 + l15;
            #pragma unroll
            for (int kk = 0; kk < 2; ++kk) {
                bf16x8 tq = *(const bf16x8*)(Qg + (size_t)qrow * rs + kk * 32 + g * 8);
                #pragma unroll
                for (int e = 0; e < 8; ++e)
                    tq[e] = (short)f2bf(bf2f((ushort_t)tq[e]) * (SCALE_ * LOG2E_));
                qf[kk] = tq;
            }
        }

        float mrow = -1e30f, lrow = 0.f;
        f32x4 oacc[4] = {};   // d-frags; D: col=d=l15, row(q-local)=g*4+r

        // prologue: load KV tile 0 into regs
        bf16x8 kvreg[2], vvreg[2];
        #pragma unroll
        for (int pass = 0; pass < 2; ++pass) {
            const ushort_t* src = Kg + (size_t)(pass * 32 + skey) * rs + sc * 8;
            kvreg[pass] = *(const bf16x8*)src;
            vvreg[pass] = *(const bf16x8*)(src + D_);
        }

        for (int kb = 0; kb < nkb; ++kb) {
            __syncthreads();   // prior compute done reading LDS
            // ---- write staged regs -> LDS (K swizzled b128, V^T scatter) ----
            #pragma unroll
            for (int pass = 0; pass < 2; ++pass) {
                const int key = pass * 32 + skey;
                *(bf16x8*)&Ks[key * 64 + ((sc ^ (key & 7)) << 3)] = kvreg[pass];
                #pragma unroll
                for (int j = 0; j < 8; ++j) {
                    const int d  = sc * 8 + j;
                    const int cp = (key >> 3) ^ (d & 7) ^ ((d >> 3) & 7);
                    Vt[d * 64 + (cp << 3) + (key & 7)] = (ushort_t)vvreg[pass][j];
                }
            }
            // ---- prefetch next KV tile into regs (hidden under compute) ----
            if (kb + 1 < nkb) {
                #pragma unroll
                for (int pass = 0; pass < 2; ++pass) {
                    const ushort_t* src =
                        Kg + (size_t)((kb + 1) * 64 + pass * 32 + skey) * rs + sc * 8;
                    kvreg[pass] = *(const bf16x8*)src;
                    vvreg[pass] = *(const bf16x8*)(src + D_);
                }
            }
            __syncthreads();   // staging visible

            // ---- S^T = K Q^T (D[key][q]: col=q=l15, row=key=g*4+r) ----
            f32x4 sf[4] = {};
            __builtin_amdgcn_s_setprio(1);
            #pragma unroll
            for (int kk = 0; kk < 2; ++kk) {
                const int cc = kk * 4 + g;
                #pragma unroll
                for (int nf = 0; nf < 4; ++nf) {
                    const int keyr = nf * 16 + l15;
                    bf16x8 kf = *(const bf16x8*)&Ks[keyr * 64 + ((cc ^ (keyr & 7)) << 3)];
                    sf[nf] = __builtin_amdgcn_mfma_f32_16x16x32_bf16(kf, qf[kk], sf[nf], 0, 0, 0);
                }
            }
            __builtin_amdgcn_s_setprio(0);

            // ---- mask (only last kv-block can cross the diagonal) ----
            if (kb == nkb - 1) {
                const int q = q0 + w * 16 + l15;
                #pragma unroll
                for (int nf = 0; nf < 4; ++nf)
                    #pragma unroll
                    for (int r = 0; r < 4; ++r)
                        if (kb * 64 + nf * 16 + g * 4 + r > q) sf[nf][r] = -1e30f;
            }
            // ---- per-row max ----
            float mx = -1e30f;
            #pragma unroll
            for (int nf = 0; nf < 4; ++nf)
                #pragma unroll
                for (int r = 0; r < 4; ++r) mx = fmaxf(mx, sf[nf][r]);
            mx = fmaxf(mx, __shfl_xor(mx, 16));
            mx = fmaxf(mx, __shfl_xor(mx, 32));

            // ---- deferred-max rescale (T13, THR=8 in log2 units) ----
            if (!__all(mx - mrow <= 8.0f)) {
                const float mnew = fmaxf(mrow, mx);
                const float corr = fexp2(mrow - mnew);
                mrow = mnew;
                lrow *= corr;
                #pragma unroll
                for (int r = 0; r < 4; ++r) {
                    const float cr = __shfl(corr, g * 4 + r, 16);
                    #pragma unroll
                    for (int nf = 0; nf < 4; ++nf) oacc[nf][r] *= cr;
                }
            }

            // ---- P = exp2(S - m), row-sum, packed write to Ps ----
            {
                const int qrow = l15;
                float psum = 0.f;
                #pragma unroll
                for (int nf = 0; nf < 4; ++nf) {
                    const float p0 = fexp2(sf[nf][0] - mrow);
                    const float p1 = fexp2(sf[nf][1] - mrow);
                    const float p2 = fexp2(sf[nf][2] - mrow);
                    const float p3 = fexp2(sf[nf][3] - mrow);
                    psum += (p0 + p1) + (p2 + p3);
                    uint2 pk = make_uint2(cvt_pk_bf16(p0, p1), cvt_pk_bf16(p2, p3));
                    const int c16 = ((nf << 1) + (g >> 1)) ^ (qrow & 7);
                    *(uint2*)((char*)Ps[w] + qrow * 128 + c16 * 16 + (g & 1) * 8) = pk;
                }
                psum += __shfl_xor(psum, 16);
                psum += __shfl_xor(psum, 32);
                lrow += psum;
            }

            // ---- O += P V (A=P from Ps, B=V^T from Vt) ----
            #pragma unroll
            for (int kk = 0; kk < 2; ++kk) {
                const int cc = kk * 4 + g;
                const int qrow = l15;
                const int c16 = cc ^ (qrow & 7);
                bf16x8 pa = *(const bf16x8*)((const char*)Ps[w] + qrow * 128 + c16 * 16);
                __builtin_amdgcn_s_setprio(1);
                #pragma unroll
                for (int nf = 0; nf < 4; ++nf) {
                    const int dr  = nf * 16 + l15;
                    const int cvp = cc ^ (dr & 7) ^ ((dr >> 3) & 7);
                    bf16x8 vf = *(const bf16x8*)&Vt[dr * 64 + (cvp << 3)];
                    oacc[nf] = __builtin_amdgcn_mfma_f32_16x16x32_bf16(pa, vf, oacc[nf], 0, 0, 0);
                }
                __builtin_amdgcn_s_setprio(0);
            }
        }

        // ---- epilogue: O = acc / l (l lives at lane l15=row; broadcast) ----
        const float linv = 1.0f / lrow;
        #pragma unroll
        for (int r = 0; r < 4; ++r) {
            const float li = __shfl(linv, g * 4 + r, 16);
            const int q = q0 + w * 16 + g * 4 + r;
            ushort_t* op = out + (size_t)(b * S_ + q) * D_ + h * HD_;
            #pragma unroll
            for (int nf = 0; nf < 4; ++nf)
                op[nf * 16 + l15] = f2bf(oacc[nf][r] * li);
        }
    }
}

// ---------------------------------------------------------------------------
// launch
// ---------------------------------------------------------------------------
extern "C" void kernel_launch(void* const* d_in, const int* in_sizes, int n_in,
                              void* d_out, int out_size, void* d_ws, size_t ws_size,
                              hipStream_t stream)
{
    const float* x   = (const float*)d_in[0];
    const float* Wq  = (const float*)d_in[1];
    const float* bq  = (const float*)d_in[2];
    const float* Wk  = (const float*)d_in[3];
    const float* bk  = (const float*)d_in[4];
    const float* Wv  = (const float*)d_in[5];
    const float* bv  = (const float*)d_in[6];
    const float* Wo  = (const float*)d_in[7];
    const float* bo  = (const float*)d_in[8];
    const float* g1  = (const float*)d_in[9];
    const float* be1 = (const float*)d_in[10];
    const float* g2  = (const float*)d_in[11];
    const float* be2 = (const float*)d_in[12];
    const float* W1  = (const float*)d_in[13];
    const float* b1  = (const float*)d_in[14];
    const float* W2  = (const float*)d_in[15];
    const float* b2  = (const float*)d_in[16];
    float* out = (float*)d_out;

    char* ws = (char*)d_ws;
    size_t o = 0;
    auto alloc = [&](size_t bytes) { size_t r = o; o = (o + bytes + 255) & ~(size_t)255; return r; };
    ushort_t* Wqkvt = (ushort_t*)(ws + alloc((size_t)3 * D_ * D_ * 2));   // [3072][1024]
    ushort_t* Wot   = (ushort_t*)(ws + alloc((size_t)D_ * D_ * 2));      // [1024][1024]
    ushort_t* W1t   = (ushort_t*)(ws + alloc((size_t)DFF_ * D_ * 2));    // [4096][1024]
    ushort_t* W2t   = (ushort_t*)(ws + alloc((size_t)D_ * DFF_ * 2));    // [1024][4096]
    float*    bqkv  = (float*)(ws + alloc((size_t)3 * D_ * 4));
    ushort_t* lnbuf = (ushort_t*)(ws + alloc((size_t)M_ * D_ * 2));      // ln1 then ln2
    ushort_t* bigbuf= (ushort_t*)(ws + alloc((size_t)M_ * DFF_ * 2));    // qkv then ffn-hidden
    ushort_t* attnb = (ushort_t*)(ws + alloc((size_t)M_ * D_ * 2));
    float*    x1    = (float*)(ws + alloc((size_t)M_ * D_ * 4));

    dim3 tblock(32, 8);
    transpose_cast_kernel<<<dim3(D_/32, D_/32), tblock, 0, stream>>>(Wq, Wqkvt,            D_, D_);
    transpose_cast_kernel<<<dim3(D_/32, D_/32), tblock, 0, stream>>>(Wk, Wqkvt + D_*D_,    D_, D_);
    transpose_cast_kernel<<<dim3(D_/32, D_/32), tblock, 0, stream>>>(Wv, Wqkvt + 2*D_*D_,  D_, D_);
    transpose_cast_kernel<<<dim3(D_/32, D_/32), tblock, 0, stream>>>(Wo, Wot,              D_, D_);
    transpose_cast_kernel<<<dim3(DFF_/32, D_/32), tblock, 0, stream>>>(W1, W1t,            D_, DFF_);
    transpose_cast_kernel<<<dim3(D_/32, DFF_/32), tblock, 0, stream>>>(W2, W2t,            DFF_, D_);
    concat_bias_kernel<<<12, 256, 0, stream>>>(bq, bk, bv, bqkv);

    // ln1
    ln_kernel<<<M_, 256, 0, stream>>>(x, g1, be1, lnbuf);
    // qkv = ln1 @ Wqkv + bqkv          [8192][3072] bf16   grid 64*24=1536
    gemm32_kernel<0><<<(M_/128)*(3*D_/128), 256, 0, stream>>>(
        lnbuf, Wqkvt, bqkv, nullptr, bigbuf, M_, 3*D_, D_, 3*D_/128);
    // flash attention (paired q-tiles)  [8192][1024] bf16
    fattn_kernel<<<dim3(S_/128, B_*H_), 256, 0, stream>>>(bigbuf, attnb);
    // x1 = x + RES*(attn @ Wo + bo)     [8192][1024] fp32  grid 64*8=512
    gemm32_kernel<2><<<(M_/128)*(D_/128), 256, 0, stream>>>(
        attnb, Wot, bo, x, x1, M_, D_, D_, D_/128);
    // ln2
    ln_kernel<<<M_, 256, 0, stream>>>(x1, g2, be2, lnbuf);
    // ffh = relu(ln2 @ W1 + b1)         [8192][4096] bf16  grid 64*32=2048
    gemm32_kernel<1><<<(M_/128)*(DFF_/128), 256, 0, stream>>>(
        lnbuf, W1t, b1, nullptr, bigbuf, M_, DFF_, D_, DFF_/128);
    // out = x1 + RES*(ffh @ W2 + b2)    [8192][1024] fp32  grid 64*8=512
    gemm32_kernel<2><<<(M_/128)*(D_/128), 256, 0, stream>>>(
        bigbuf, W2t, b2, x1, out, M_, D_, DFF_, D_/128);
}

// Round 9
// 470.355 us; speedup vs baseline: 1.0245x; 1.0245x over previous
//
#include <hip/hip_runtime.h>

typedef unsigned short ushort_t;
typedef unsigned int uint32;
typedef __attribute__((ext_vector_type(4))) float f32x4;
typedef __attribute__((ext_vector_type(8))) short bf16x8;

#define B_   4
#define S_   2048
#define D_   1024
#define H_   16
#define HD_  64
#define DFF_ 4096
#define M_   (B_ * S_)          // 8192 rows (tokens)

#define RES_   0.28867513459481287f   // 1/sqrt(12)
#define SCALE_ 0.03125f               // 1/sqrt(1024)
#define EPS_   1e-5f
#define LOG2E_ 1.4426950408889634f

__device__ __forceinline__ ushort_t f2bf(float f) {
    union { float f; uint32 u; } c; c.f = f;
    uint32 u = c.u + 0x7fffu + ((c.u >> 16) & 1u);
    return (ushort_t)(u >> 16);
}
__device__ __forceinline__ float bf2f(ushort_t h) {
    union { uint32 u; float f; } c; c.u = ((uint32)h) << 16;
    return c.f;
}
__device__ __forceinline__ float fexp2(float x) {
    float r; asm("v_exp_f32 %0, %1" : "=v"(r) : "v"(x)); return r;
}
__device__ __forceinline__ uint32 cvt_pk_bf16(float lo, float hi) {
    uint32 r;
    asm("v_cvt_pk_bf16_f32 %0, %1, %2" : "=v"(r) : "v"(lo), "v"(hi));
    return r;
}

#define GLDS(src_, dst_)                                                     \
    __builtin_amdgcn_global_load_lds(                                        \
        (const __attribute__((address_space(1))) void*)(src_),               \
        (__attribute__((address_space(3))) void*)(dst_), 16, 0, 0)

// ---------------------------------------------------------------------------
// Transpose + fp32->bf16 cast:  W[K][N] (fp32, row-major) -> Wt[N][K] (bf16)
// ---------------------------------------------------------------------------
__global__ __launch_bounds__(256) void transpose_cast_kernel(
    const float* __restrict__ W, ushort_t* __restrict__ Wt, int K, int N)
{
    __shared__ float tile[32][33];
    const int bx = blockIdx.x * 32;  // N offset
    const int by = blockIdx.y * 32;  // K offset
    const int tx = threadIdx.x;      // 0..31
    const int ty = threadIdx.y;      // 0..7
    #pragma unroll
    for (int i = 0; i < 32; i += 8)
        tile[ty + i][tx] = W[(size_t)(by + ty + i) * N + bx + tx];
    __syncthreads();
    #pragma unroll
    for (int i = 0; i < 32; i += 8)
        Wt[(size_t)(bx + ty + i) * K + by + tx] = f2bf(tile[tx][ty + i]);
}

// ---------------------------------------------------------------------------
// Concat bq,bk,bv -> bqkv[3072]
// ---------------------------------------------------------------------------
__global__ void concat_bias_kernel(const float* __restrict__ bq,
                                   const float* __restrict__ bk,
                                   const float* __restrict__ bv,
                                   float* __restrict__ bqkv)
{
    int i = blockIdx.x * blockDim.x + threadIdx.x;
    if (i < 3 * D_) {
        float v = (i < D_) ? bq[i] : (i < 2 * D_) ? bk[i - D_] : bv[i - 2 * D_];
        bqkv[i] = v;
    }
}

// ---------------------------------------------------------------------------
// LayerNorm: fp32 in [rows][1024] -> bf16 out
// ---------------------------------------------------------------------------
__global__ __launch_bounds__(256) void ln_kernel(
    const float* __restrict__ x, const float* __restrict__ g,
    const float* __restrict__ be, ushort_t* __restrict__ out)
{
    const int row = blockIdx.x;
    const int t = threadIdx.x;
    const int lane = t & 63;
    const int wave = t >> 6;
    const float4* xr = (const float4*)(x + (size_t)row * D_);
    float4 v = xr[t];
    float s  = v.x + v.y + v.z + v.w;
    float s2 = v.x * v.x + v.y * v.y + v.z * v.z + v.w * v.w;
    #pragma unroll
    for (int off = 32; off; off >>= 1) {
        s  += __shfl_xor(s, off);
        s2 += __shfl_xor(s2, off);
    }
    __shared__ float red[8];
    if (lane == 0) { red[wave * 2] = s; red[wave * 2 + 1] = s2; }
    __syncthreads();
    s  = red[0] + red[2] + red[4] + red[6];
    s2 = red[1] + red[3] + red[5] + red[7];
    const float mean = s * (1.0f / D_);
    const float var  = s2 * (1.0f / D_) - mean * mean;
    const float rstd = rsqrtf(var + EPS_);
    const float4 gv  = ((const float4*)g)[t];
    const float4 bv  = ((const float4*)be)[t];
    ushort_t o[4];
    o[0] = f2bf((v.x - mean) * rstd * gv.x + bv.x);
    o[1] = f2bf((v.y - mean) * rstd * gv.y + bv.y);
    o[2] = f2bf((v.z - mean) * rstd * gv.z + bv.z);
    o[3] = f2bf((v.w - mean) * rstd * gv.w + bv.w);
    *(ushort2*)&out[(size_t)row * D_ + t * 4]     = make_ushort2(o[0], o[1]);
    *(ushort2*)&out[(size_t)row * D_ + t * 4 + 2] = make_ushort2(o[2], o[3]);
}

// ---------------------------------------------------------------------------
// GEMM v6: C[M][N] = epilogue(A[M][K] @ Bt[N][K]^T + bias)
// BM=256, BN=128, BK=32, 4 waves (2M x 2N, per-wave 128x64 = 8x4 16x16x32
// frags -> ds_read:MFMA = 12:32, MFMA-pipe-balanced).
// 3-deep LDS rotation (72KB -> 2 blocks/CU), counted vmcnt(6).
// Swizzle: stored chunk = logical ^ ((row>>1)&3)  [bank-quartet-exact:
// quartet=(row*4+c)%8; even/odd rows split halves, (row>>1)&3 rotates within]
// Applied per rule #21: linear LDS dest + inverse-swizzled GLOBAL src +
// swizzled ds_read. T1 bijective XCD swizzle (grids % 8 == 0), T5 setprio.
// ---------------------------------------------------------------------------
template <int MODE>
__global__ __launch_bounds__(256, 2) void gemmW_kernel(
    const ushort_t* __restrict__ A, const ushort_t* __restrict__ Bt,
    const float* __restrict__ bias, const float* __restrict__ res,
    void* __restrict__ Cout, int M, int N, int K, int gx)
{
    __shared__ __align__(16) ushort_t As[3][256 * 32];   // 16KB x3
    __shared__ __align__(16) ushort_t Bs[3][128 * 32];   // 8KB x3

    const int tid  = threadIdx.x;
    const int w    = tid >> 6;
    const int lane = tid & 63;
    const int l15  = lane & 15;
    const int g    = lane >> 4;          // 0..3 : k-chunk of the frag

    // T1: bijective XCD swizzle (gridDim.x % 8 == 0)
    const int cpx = gridDim.x >> 3;
    const int swz = (blockIdx.x & 7) * cpx + (blockIdx.x >> 3);
    const int bx = swz % gx, by = swz / gx;
    const int m0 = by * 256, n0 = bx * 128;

    const int mw = (w >> 1) * 128;       // 0,128
    const int nw = (w & 1) * 64;         // 0,64

    // staging: A = 1024 16B-chunks (4/thread), B = 512 (2/thread).
    // LDS pos L (linear, chunk L at byte L*16): row = L>>2, stored c = L&3.
    // stored c at row r holds logical c ^ ((r>>1)&3) -> pre-swizzle source.
    const ushort_t* srcA[4];
    const ushort_t* srcB[2];
    int ldsA[4], ldsB[2];
    #pragma unroll
    for (int p = 0; p < 4; ++p) {
        const int L = p * 256 + tid;
        const int row = L >> 2;
        srcA[p] = A + (size_t)(m0 + row) * K + (((L & 3) ^ ((row >> 1) & 3)) << 3);
        ldsA[p] = (p * 256 + w * 64) * 8;    // wave-uniform; HW adds lane*16B
    }
    #pragma unroll
    for (int p = 0; p < 2; ++p) {
        const int L = p * 256 + tid;
        const int row = L >> 2;
        srcB[p] = Bt + (size_t)(n0 + row) * K + (((L & 3) ^ ((row >> 1) & 3)) << 3);
        ldsB[p] = (p * 256 + w * 64) * 8;
    }

    #define STAGE(t_, buf_)                                                  \
        do {                                                                 \
            GLDS(srcA[0] + (size_t)(t_) * 32, &As[buf_][ldsA[0]]);           \
            GLDS(srcA[1] + (size_t)(t_) * 32, &As[buf_][ldsA[1]]);           \
            GLDS(srcA[2] + (size_t)(t_) * 32, &As[buf_][ldsA[2]]);           \
            GLDS(srcA[3] + (size_t)(t_) * 32, &As[buf_][ldsA[3]]);           \
            GLDS(srcB[0] + (size_t)(t_) * 32, &Bs[buf_][ldsB[0]]);           \
            GLDS(srcB[1] + (size_t)(t_) * 32, &Bs[buf_][ldsB[1]]);           \
        } while (0)

    f32x4 acc[8][4] = {};
    const int NT = K >> 5;

    STAGE(0, 0);
    STAGE(1, 1);
    asm volatile("s_waitcnt vmcnt(6)" ::: "memory");   // tile0 landed
    __builtin_amdgcn_s_barrier();

    for (int t = 0; t < NT; ++t) {
        const int cur = t % 3;
        const bool more = (t + 2 < NT);
        if (more) STAGE(t + 2, (t + 2) % 3);

        // frag reads: stored chunk = g ^ ((row>>1)&3)  (uniform in mf/nf)
        bf16x8 af[8], bfr[4];
        #pragma unroll
        for (int mf = 0; mf < 8; ++mf) {
            const int row = mw + mf * 16 + l15;
            af[mf] = *(const bf16x8*)&As[cur][row * 32 + ((g ^ ((row >> 1) & 3)) << 3)];
        }
        #pragma unroll
        for (int nf = 0; nf < 4; ++nf) {
            const int row = nw + nf * 16 + l15;
            bfr[nf] = *(const bf16x8*)&Bs[cur][row * 32 + ((g ^ ((row >> 1) & 3)) << 3)];
        }

        __builtin_amdgcn_s_setprio(1);
        #pragma unroll
        for (int mf = 0; mf < 8; ++mf)
            #pragma unroll
            for (int nf = 0; nf < 4; ++nf)
                acc[mf][nf] = __builtin_amdgcn_mfma_f32_16x16x32_bf16(
                    af[mf], bfr[nf], acc[mf][nf], 0, 0, 0);
        __builtin_amdgcn_s_setprio(0);

        if (more)
            asm volatile("s_waitcnt vmcnt(6)" ::: "memory");  // t+1 ready
        else
            asm volatile("s_waitcnt vmcnt(0)" ::: "memory");
        __builtin_amdgcn_s_barrier();
    }
    #undef STAGE

    // epilogue: C/D layout col = lane&15, row = (lane>>4)*4 + r
    const int rbase = g * 4;
    #pragma unroll
    for (int mf = 0; mf < 8; ++mf) {
        #pragma unroll
        for (int nf = 0; nf < 4; ++nf) {
            const int col = n0 + nw + nf * 16 + l15;
            const float bcol = bias[col];
            #pragma unroll
            for (int r = 0; r < 4; ++r) {
                const int row = m0 + mw + mf * 16 + rbase + r;
                float v = acc[mf][nf][r] + bcol;
                const size_t idx = (size_t)row * N + col;
                if (MODE == 0) {
                    ((ushort_t*)Cout)[idx] = f2bf(v);
                } else if (MODE == 1) {
                    ((ushort_t*)Cout)[idx] = f2bf(fmaxf(v, 0.0f));
                } else {
                    ((float*)Cout)[idx] = res[idx] + RES_ * v;
                }
            }
        }
    }
}

// ---------------------------------------------------------------------------
// Flash attention v5 (causal) from packed qkv (bf16 [8192][3072]).
// - 64-row q-tiles, 4 waves x 16 rows; paired triangle (uniform 33 iters)
// - swapped QK^T, reg-prefetch staging (T14), exp2 softmax, defer-max (T13)
// out: bf16 [8192][1024]
// ---------------------------------------------------------------------------
__global__ __launch_bounds__(256) void fattn_kernel(
    const ushort_t* __restrict__ qkv, ushort_t* __restrict__ out)
{
    __shared__ __align__(16) ushort_t Ks[64 * 64];     // [key][d], chunk c^=key&7
    __shared__ __align__(16) ushort_t Vt[64 * 64];     // [d][key], chunk c^=(d&7)^((d>>3)&7)
    __shared__ __align__(16) ushort_t Ps[4][16 * 64];  // per-wave [q][key], 16B-chunk c16^=q&7

    const int tid  = threadIdx.x;
    const int lane = tid & 63;
    const int w    = tid >> 6;
    const int bh = blockIdx.y;
    const int b = bh >> 4, h = bh & 15;

    const int l15 = lane & 15;
    const int g   = lane >> 4;

    const size_t rs = 3 * D_;
    const ushort_t* Qg = qkv + (size_t)b * S_ * rs + h * HD_;
    const ushort_t* Kg = Qg + D_;

    // staging geometry (constant per thread)
    const int skey = tid >> 3;          // 0..31 (+32 on pass 1)
    const int sc   = tid & 7;           // 16B chunk within row

    #pragma unroll
    for (int half = 0; half < 2; ++half) {
        const int qt = half ? blockIdx.x : (S_ / 64 - 1) - blockIdx.x;
        const int q0 = qt * 64;
        const int nkb = qt + 1;

        // Q B-frags (col=q=l15, k=g*8+e +kk*32), pre-scaled by SCALE_*log2e
        bf16x8 qf[2];
        {
            const int qrow = q0 + w * 16 + l15;
            #pragma unroll
            for (int kk = 0; kk < 2; ++kk) {
                bf16x8 tq = *(const bf16x8*)(Qg + (size_t)qrow * rs + kk * 32 + g * 8);
                #pragma unroll
                for (int e = 0; e < 8; ++e)
                    tq[e] = (short)f2bf(bf2f((ushort_t)tq[e]) * (SCALE_ * LOG2E_));
                qf[kk] = tq;
            }
        }

        float mrow = -1e30f, lrow = 0.f;
        f32x4 oacc[4] = {};   // d-frags; D: col=d=l15, row(q-local)=g*4+r

        // prologue: load KV tile 0 into regs
        bf16x8 kvreg[2], vvreg[2];
        #pragma unroll
        for (int pass = 0; pass < 2; ++pass) {
            const ushort_t* src = Kg + (size_t)(pass * 32 + skey) * rs + sc * 8;
            kvreg[pass] = *(const bf16x8*)src;
            vvreg[pass] = *(const bf16x8*)(src + D_);
        }

        for (int kb = 0; kb < nkb; ++kb) {
            __syncthreads();   // prior compute done reading LDS
            // ---- write staged regs -> LDS (K swizzled b128, V^T scatter) ----
            #pragma unroll
            for (int pass = 0; pass < 2; ++pass) {
                const int key = pass * 32 + skey;
                *(bf16x8*)&Ks[key * 64 + ((sc ^ (key & 7)) << 3)] = kvreg[pass];
                #pragma unroll
                for (int j = 0; j < 8; ++j) {
                    const int d  = sc * 8 + j;
                    const int cp = (key >> 3) ^ (d & 7) ^ ((d >> 3) & 7);
                    Vt[d * 64 + (cp << 3) + (key & 7)] = (ushort_t)vvreg[pass][j];
                }
            }
            // ---- prefetch next KV tile into regs (hidden under compute) ----
            if (kb + 1 < nkb) {
                #pragma unroll
                for (int pass = 0; pass < 2; ++pass) {
                    const ushort_t* src =
                        Kg + (size_t)((kb + 1) * 64 + pass * 32 + skey) * rs + sc * 8;
                    kvreg[pass] = *(const bf16x8*)src;
                    vvreg[pass] = *(const bf16x8*)(src + D_);
                }
            }
            __syncthreads();   // staging visible

            // ---- S^T = K Q^T (D[key][q]: col=q=l15, row=key=g*4+r) ----
            f32x4 sf[4] = {};
            __builtin_amdgcn_s_setprio(1);
            #pragma unroll
            for (int kk = 0; kk < 2; ++kk) {
                const int cc = kk * 4 + g;
                #pragma unroll
                for (int nf = 0; nf < 4; ++nf) {
                    const int keyr = nf * 16 + l15;
                    bf16x8 kf = *(const bf16x8*)&Ks[keyr * 64 + ((cc ^ (keyr & 7)) << 3)];
                    sf[nf] = __builtin_amdgcn_mfma_f32_16x16x32_bf16(kf, qf[kk], sf[nf], 0, 0, 0);
                }
            }
            __builtin_amdgcn_s_setprio(0);

            // ---- mask (only last kv-block can cross the diagonal) ----
            if (kb == nkb - 1) {
                const int q = q0 + w * 16 + l15;
                #pragma unroll
                for (int nf = 0; nf < 4; ++nf)
                    #pragma unroll
                    for (int r = 0; r < 4; ++r)
                        if (kb * 64 + nf * 16 + g * 4 + r > q) sf[nf][r] = -1e30f;
            }
            // ---- per-row max ----
            float mx = -1e30f;
            #pragma unroll
            for (int nf = 0; nf < 4; ++nf)
                #pragma unroll
                for (int r = 0; r < 4; ++r) mx = fmaxf(mx, sf[nf][r]);
            mx = fmaxf(mx, __shfl_xor(mx, 16));
            mx = fmaxf(mx, __shfl_xor(mx, 32));

            // ---- deferred-max rescale (T13, THR=8 in log2 units) ----
            if (!__all(mx - mrow <= 8.0f)) {
                const float mnew = fmaxf(mrow, mx);
                const float corr = fexp2(mrow - mnew);
                mrow = mnew;
                lrow *= corr;
                #pragma unroll
                for (int r = 0; r < 4; ++r) {
                    const float cr = __shfl(corr, g * 4 + r, 16);
                    #pragma unroll
                    for (int nf = 0; nf < 4; ++nf) oacc[nf][r] *= cr;
                }
            }

            // ---- P = exp2(S - m), row-sum, packed write to Ps ----
            {
                const int qrow = l15;
                float psum = 0.f;
                #pragma unroll
                for (int nf = 0; nf < 4; ++nf) {
                    const float p0 = fexp2(sf[nf][0] - mrow);
                    const float p1 = fexp2(sf[nf][1] - mrow);
                    const float p2 = fexp2(sf[nf][2] - mrow);
                    const float p3 = fexp2(sf[nf][3] - mrow);
                    psum += (p0 + p1) + (p2 + p3);
                    uint2 pk = make_uint2(cvt_pk_bf16(p0, p1), cvt_pk_bf16(p2, p3));
                    const int c16 = ((nf << 1) + (g >> 1)) ^ (qrow & 7);
                    *(uint2*)((char*)Ps[w] + qrow * 128 + c16 * 16 + (g & 1) * 8) = pk;
                }
                psum += __shfl_xor(psum, 16);
                psum += __shfl_xor(psum, 32);
                lrow += psum;
            }

            // ---- O += P V (A=P from Ps, B=V^T from Vt) ----
            #pragma unroll
            for (int kk = 0; kk < 2; ++kk) {
                const int cc = kk * 4 + g;
                const int qrow = l15;
                const int c16 = cc ^ (qrow & 7);
                bf16x8 pa = *(const bf16x8*)((const char*)Ps[w] + qrow * 128 + c16 * 16);
                __builtin_amdgcn_s_setprio(1);
                #pragma unroll
                for (int nf = 0; nf < 4; ++nf) {
                    const int dr  = nf * 16 + l15;
                    const int cvp = cc ^ (dr & 7) ^ ((dr >> 3) & 7);
                    bf16x8 vf = *(const bf16x8*)&Vt[dr * 64 + (cvp << 3)];
                    oacc[nf] = __builtin_amdgcn_mfma_f32_16x16x32_bf16(pa, vf, oacc[nf], 0, 0, 0);
                }
                __builtin_amdgcn_s_setprio(0);
            }
        }

        // ---- epilogue: O = acc / l (l lives at lane l15=row; broadcast) ----
        const float linv = 1.0f / lrow;
        #pragma unroll
        for (int r = 0; r < 4; ++r) {
            const float li = __shfl(linv, g * 4 + r, 16);
            const int q = q0 + w * 16 + g * 4 + r;
            ushort_t* op = out + (size_t)(b * S_ + q) * D_ + h * HD_;
            #pragma unroll
            for (int nf = 0; nf < 4; ++nf)
                op[nf * 16 + l15] = f2bf(oacc[nf][r] * li);
        }
    }
}

// ---------------------------------------------------------------------------
// launch
// ---------------------------------------------------------------------------
extern "C" void kernel_launch(void* const* d_in, const int* in_sizes, int n_in,
                              void* d_out, int out_size, void* d_ws, size_t ws_size,
                              hipStream_t stream)
{
    const float* x   = (const float*)d_in[0];
    const float* Wq  = (const float*)d_in[1];
    const float* bq  = (const float*)d_in[2];
    const float* Wk  = (const float*)d_in[3];
    const float* bk  = (const float*)d_in[4];
    const float* Wv  = (const float*)d_in[5];
    const float* bv  = (const float*)d_in[6];
    const float* Wo  = (const float*)d_in[7];
    const float* bo  = (const float*)d_in[8];
    const float* g1  = (const float*)d_in[9];
    const float* be1 = (const float*)d_in[10];
    const float* g2  = (const float*)d_in[11];
    const float* be2 = (const float*)d_in[12];
    const float* W1  = (const float*)d_in[13];
    const float* b1  = (const float*)d_in[14];
    const float* W2  = (const float*)d_in[15];
    const float* b2  = (const float*)d_in[16];
    float* out = (float*)d_out;

    char* ws = (char*)d_ws;
    size_t o = 0;
    auto alloc = [&](size_t bytes) { size_t r = o; o = (o + bytes + 255) & ~(size_t)255; return r; };
    ushort_t* Wqkvt = (ushort_t*)(ws + alloc((size_t)3 * D_ * D_ * 2));   // [3072][1024]
    ushort_t* Wot   = (ushort_t*)(ws + alloc((size_t)D_ * D_ * 2));      // [1024][1024]
    ushort_t* W1t   = (ushort_t*)(ws + alloc((size_t)DFF_ * D_ * 2));    // [4096][1024]
    ushort_t* W2t   = (ushort_t*)(ws + alloc((size_t)D_ * DFF_ * 2));    // [1024][4096]
    float*    bqkv  = (float*)(ws + alloc((size_t)3 * D_ * 4));
    ushort_t* lnbuf = (ushort_t*)(ws + alloc((size_t)M_ * D_ * 2));      // ln1 then ln2
    ushort_t* bigbuf= (ushort_t*)(ws + alloc((size_t)M_ * DFF_ * 2));    // qkv then ffn-hidden
    ushort_t* attnb = (ushort_t*)(ws + alloc((size_t)M_ * D_ * 2));
    float*    x1    = (float*)(ws + alloc((size_t)M_ * D_ * 4));

    dim3 tblock(32, 8);
    transpose_cast_kernel<<<dim3(D_/32, D_/32), tblock, 0, stream>>>(Wq, Wqkvt,            D_, D_);
    transpose_cast_kernel<<<dim3(D_/32, D_/32), tblock, 0, stream>>>(Wk, Wqkvt + D_*D_,    D_, D_);
    transpose_cast_kernel<<<dim3(D_/32, D_/32), tblock, 0, stream>>>(Wv, Wqkvt + 2*D_*D_,  D_, D_);
    transpose_cast_kernel<<<dim3(D_/32, D_/32), tblock, 0, stream>>>(Wo, Wot,              D_, D_);
    transpose_cast_kernel<<<dim3(DFF_/32, D_/32), tblock, 0, stream>>>(W1, W1t,            D_, DFF_);
    transpose_cast_kernel<<<dim3(D_/32, DFF_/32), tblock, 0, stream>>>(W2, W2t,            DFF_, D_);
    concat_bias_kernel<<<12, 256, 0, stream>>>(bq, bk, bv, bqkv);

    // ln1
    ln_kernel<<<M_, 256, 0, stream>>>(x, g1, be1, lnbuf);
    // qkv = ln1 @ Wqkv + bqkv          [8192][3072] bf16   grid 32*24=768
    gemmW_kernel<0><<<(M_/256)*(3*D_/128), 256, 0, stream>>>(
        lnbuf, Wqkvt, bqkv, nullptr, bigbuf, M_, 3*D_, D_, 3*D_/128);
    // flash attention (paired q-tiles)  [8192][1024] bf16
    fattn_kernel<<<dim3(S_/128, B_*H_), 256, 0, stream>>>(bigbuf, attnb);
    // x1 = x + RES*(attn @ Wo + bo)     [8192][1024] fp32  grid 32*8=256
    gemmW_kernel<2><<<(M_/256)*(D_/128), 256, 0, stream>>>(
        attnb, Wot, bo, x, x1, M_, D_, D_, D_/128);
    // ln2
    ln_kernel<<<M_, 256, 0, stream>>>(x1, g2, be2, lnbuf);
    // ffh = relu(ln2 @ W1 + b1)         [8192][4096] bf16  grid 32*32=1024
    gemmW_kernel<1><<<(M_/256)*(DFF_/128), 256, 0, stream>>>(
        lnbuf, W1t, b1, nullptr, bigbuf, M_, DFF_, D_, DFF_/128);
    // out = x1 + RES*(ffh @ W2 + b2)    [8192][1024] fp32  grid 32*8=256
    gemmW_kernel<2><<<(M_/256)*(D_/128), 256, 0, stream>>>(
        bigbuf, W2t, b2, x1, out, M_, D_, DFF_, D_/128);
}

// Round 10
// 388.205 us; speedup vs baseline: 1.2412x; 1.2116x over previous
//
#include <hip/hip_runtime.h>

typedef unsigned short ushort_t;
typedef unsigned int uint32;
typedef __attribute__((ext_vector_type(4))) float f32x4;
typedef __attribute__((ext_vector_type(8))) short bf16x8;

#define B_   4
#define S_   2048
#define D_   1024
#define H_   16
#define HD_  64
#define DFF_ 4096
#define M_   (B_ * S_)          // 8192 rows (tokens)

#define RES_   0.28867513459481287f   // 1/sqrt(12)
#define SCALE_ 0.03125f               // 1/sqrt(1024)
#define EPS_   1e-5f
#define LOG2E_ 1.4426950408889634f

__device__ __forceinline__ ushort_t f2bf(float f) {
    union { float f; uint32 u; } c; c.f = f;
    uint32 u = c.u + 0x7fffu + ((c.u >> 16) & 1u);
    return (ushort_t)(u >> 16);
}
__device__ __forceinline__ float bf2f(ushort_t h) {
    union { uint32 u; float f; } c; c.u = ((uint32)h) << 16;
    return c.f;
}
__device__ __forceinline__ float fexp2(float x) {
    float r; asm("v_exp_f32 %0, %1" : "=v"(r) : "v"(x)); return r;
}
__device__ __forceinline__ uint32 cvt_pk_bf16(float lo, float hi) {
    uint32 r;
    asm("v_cvt_pk_bf16_f32 %0, %1, %2" : "=v"(r) : "v"(lo), "v"(hi));
    return r;
}

#define GLDS(src_, dst_)                                                     \
    __builtin_amdgcn_global_load_lds(                                        \
        (const __attribute__((address_space(1))) void*)(src_),               \
        (__attribute__((address_space(3))) void*)(dst_), 16, 0, 0)

// ---------------------------------------------------------------------------
// Transpose + fp32->bf16 cast:  W[K][N] (fp32, row-major) -> Wt[N][K] (bf16)
// ---------------------------------------------------------------------------
__global__ __launch_bounds__(256) void transpose_cast_kernel(
    const float* __restrict__ W, ushort_t* __restrict__ Wt, int K, int N)
{
    __shared__ float tile[32][33];
    const int bx = blockIdx.x * 32;  // N offset
    const int by = blockIdx.y * 32;  // K offset
    const int tx = threadIdx.x;      // 0..31
    const int ty = threadIdx.y;      // 0..7
    #pragma unroll
    for (int i = 0; i < 32; i += 8)
        tile[ty + i][tx] = W[(size_t)(by + ty + i) * N + bx + tx];
    __syncthreads();
    #pragma unroll
    for (int i = 0; i < 32; i += 8)
        Wt[(size_t)(bx + ty + i) * K + by + tx] = f2bf(tile[tx][ty + i]);
}

// ---------------------------------------------------------------------------
// Concat bq,bk,bv -> bqkv[3072]
// ---------------------------------------------------------------------------
__global__ void concat_bias_kernel(const float* __restrict__ bq,
                                   const float* __restrict__ bk,
                                   const float* __restrict__ bv,
                                   float* __restrict__ bqkv)
{
    int i = blockIdx.x * blockDim.x + threadIdx.x;
    if (i < 3 * D_) {
        float v = (i < D_) ? bq[i] : (i < 2 * D_) ? bk[i - D_] : bv[i - 2 * D_];
        bqkv[i] = v;
    }
}

// ---------------------------------------------------------------------------
// LayerNorm: fp32 in [rows][1024] -> bf16 out
// ---------------------------------------------------------------------------
__global__ __launch_bounds__(256) void ln_kernel(
    const float* __restrict__ x, const float* __restrict__ g,
    const float* __restrict__ be, ushort_t* __restrict__ out)
{
    const int row = blockIdx.x;
    const int t = threadIdx.x;
    const int lane = t & 63;
    const int wave = t >> 6;
    const float4* xr = (const float4*)(x + (size_t)row * D_);
    float4 v = xr[t];
    float s  = v.x + v.y + v.z + v.w;
    float s2 = v.x * v.x + v.y * v.y + v.z * v.z + v.w * v.w;
    #pragma unroll
    for (int off = 32; off; off >>= 1) {
        s  += __shfl_xor(s, off);
        s2 += __shfl_xor(s2, off);
    }
    __shared__ float red[8];
    if (lane == 0) { red[wave * 2] = s; red[wave * 2 + 1] = s2; }
    __syncthreads();
    s  = red[0] + red[2] + red[4] + red[6];
    s2 = red[1] + red[3] + red[5] + red[7];
    const float mean = s * (1.0f / D_);
    const float var  = s2 * (1.0f / D_) - mean * mean;
    const float rstd = rsqrtf(var + EPS_);
    const float4 gv  = ((const float4*)g)[t];
    const float4 bv  = ((const float4*)be)[t];
    ushort_t o[4];
    o[0] = f2bf((v.x - mean) * rstd * gv.x + bv.x);
    o[1] = f2bf((v.y - mean) * rstd * gv.y + bv.y);
    o[2] = f2bf((v.z - mean) * rstd * gv.z + bv.z);
    o[3] = f2bf((v.w - mean) * rstd * gv.w + bv.w);
    *(ushort2*)&out[(size_t)row * D_ + t * 4]     = make_ushort2(o[0], o[1]);
    *(ushort2*)&out[(size_t)row * D_ + t * 4 + 2] = make_ushort2(o[2], o[3]);
}

// ---------------------------------------------------------------------------
// GEMM v7: C[M][N] = epilogue(A[M][K] @ Bt[N][K]^T + bias)
// BN=256, BK=32, 8 waves (2M x 4N), 512 thr.
//   BM=256: per-wave 128x64 (8x4 frags), 2 phases/K-tile of 16 MFMA each,
//           LDS 3buf x (16+16)KB = 96KB -> 1 block/CU.
//   BM=128: per-wave 64x64 (4x4 frags), 1 phase/K-tile (16 MFMA),
//           LDS 3buf x (8+16)KB = 72KB -> 2 blocks/CU (16 waves).
// 3-buffer rotation => staging never targets a buffer being read.
// Counted vmcnt(LOADS) once per K-tile (t+2's loads stay in flight).
// Swizzle: stored chunk = logical ^ ((row>>1)&3) [quartet-exact, 2-way free;
// verified 0-conflict in R8]; linear LDS dest + inverse-swizzled global src.
// T1 bijective XCD swizzle (grids % 8 == 0), T5 setprio.
// ---------------------------------------------------------------------------
template <int MODE, int BM>
__global__ __launch_bounds__(512, (BM == 256) ? 1 : 2) void gemmT_kernel(
    const ushort_t* __restrict__ A, const ushort_t* __restrict__ Bt,
    const float* __restrict__ bias, const float* __restrict__ res,
    void* __restrict__ Cout, int M, int N, int K, int gx)
{
    constexpr int MF     = BM / 32;        // m-frags per wave (8 or 4)
    constexpr int ALOADS = BM / 128;       // A gloads per thread (2 or 1)
    constexpr int LOADS  = ALOADS + 2;     // gloads per K-tile per thread

    __shared__ __align__(16) ushort_t As[3][BM * 32];
    __shared__ __align__(16) ushort_t Bs[3][256 * 32];

    const int tid  = threadIdx.x;
    const int w    = tid >> 6;
    const int lane = tid & 63;
    const int l15  = lane & 15;
    const int g    = lane >> 4;

    // T1: bijective XCD swizzle (gridDim.x % 8 == 0)
    const int cpx = gridDim.x >> 3;
    const int swz = (blockIdx.x & 7) * cpx + (blockIdx.x >> 3);
    const int bx = swz % gx, by = swz / gx;
    const int m0 = by * BM, n0 = bx * 256;

    const int wm = (w >> 2) * (BM / 2);    // 2 M-waves
    const int wn = (w & 3) * 64;           // 4 N-waves

    // staging: chunk L at LDS byte L*16 (linear); row = L>>2, stored c = L&3
    // holds logical chunk (L&3)^((row>>1)&3) -> pre-swizzled global source.
    const ushort_t* srcA[ALOADS];
    int ldsA[ALOADS];
    const ushort_t* srcB[2];
    int ldsB[2];
    #pragma unroll
    for (int p = 0; p < ALOADS; ++p) {
        const int L = p * 512 + tid;
        const int row = L >> 2;
        srcA[p] = A + (size_t)(m0 + row) * K + (((L & 3) ^ ((row >> 1) & 3)) << 3);
        ldsA[p] = (p * 512 + w * 64) * 8;      // wave-uniform; HW adds lane*16B
    }
    #pragma unroll
    for (int p = 0; p < 2; ++p) {
        const int L = p * 512 + tid;
        const int row = L >> 2;
        srcB[p] = Bt + (size_t)(n0 + row) * K + (((L & 3) ^ ((row >> 1) & 3)) << 3);
        ldsB[p] = (p * 512 + w * 64) * 8;
    }

    #define STAGE_A(koff_, buf_)                                             \
        do { _Pragma("unroll")                                               \
             for (int p = 0; p < ALOADS; ++p)                                \
                 GLDS(srcA[p] + (koff_), &As[buf_][ldsA[p]]); } while (0)
    #define STAGE_B(koff_, buf_)                                             \
        do { _Pragma("unroll")                                               \
             for (int p = 0; p < 2; ++p)                                     \
                 GLDS(srcB[p] + (koff_), &Bs[buf_][ldsB[p]]); } while (0)

    // frag reads (swizzled chunk)
    #define LDA(mf_) (*(const bf16x8*)&As[cur][(wm + (mf_) * 16 + l15) * 32 + \
                        ((g ^ (((wm + (mf_) * 16 + l15) >> 1) & 3)) << 3)])
    #define LDB(nf_) (*(const bf16x8*)&Bs[cur][(wn + (nf_) * 16 + l15) * 32 + \
                        ((g ^ (((wn + (nf_) * 16 + l15) >> 1) & 3)) << 3)])

    f32x4 acc[MF][4] = {};
    const int NT = K >> 5;

    STAGE_A(0, 0); STAGE_B(0, 0);
    STAGE_A(32, 1); STAGE_B(32, 1);
    asm volatile("s_waitcnt vmcnt(%0)" :: "n"(LOADS) : "memory");  // tile0 in
    __builtin_amdgcn_s_barrier();

    for (int t = 0; t < NT; ++t) {
        const int cur = t % 3;
        const int nb  = (t + 2) % 3;
        const bool more = (t + 2 < NT);
        const size_t koff = (size_t)(t + 2) * 32;

        bf16x8 af[4], bfr[4];
        #pragma unroll
        for (int nf = 0; nf < 4; ++nf) bfr[nf] = LDB(nf);
        #pragma unroll
        for (int mf = 0; mf < 4; ++mf) af[mf] = LDA(mf);

        if (BM == 256) {
            // ---- phase 0: MFMA mf0-3; stage A(t+2) ----
            if (more) STAGE_A(koff, nb);
            __builtin_amdgcn_s_barrier();
            __builtin_amdgcn_s_setprio(1);
            #pragma unroll
            for (int mf = 0; mf < 4; ++mf)
                #pragma unroll
                for (int nf = 0; nf < 4; ++nf)
                    acc[mf][nf] = __builtin_amdgcn_mfma_f32_16x16x32_bf16(
                        af[mf], bfr[nf], acc[mf][nf], 0, 0, 0);
            __builtin_amdgcn_s_setprio(0);
            __builtin_amdgcn_s_barrier();

            // ---- phase 1: MFMA mf4-7; stage B(t+2); counted vmcnt ----
            #pragma unroll
            for (int mf = 0; mf < 4; ++mf) af[mf] = LDA(mf + 4);
            if (more) STAGE_B(koff, nb);
            __builtin_amdgcn_s_barrier();
            __builtin_amdgcn_s_setprio(1);
            #pragma unroll
            for (int mf = 0; mf < 4; ++mf)
                #pragma unroll
                for (int nf = 0; nf < 4; ++nf)
                    acc[(MF == 8 ? mf + 4 : mf)][nf] =
                        __builtin_amdgcn_mfma_f32_16x16x32_bf16(
                            af[mf], bfr[nf], acc[(MF == 8 ? mf + 4 : mf)][nf], 0, 0, 0);
            __builtin_amdgcn_s_setprio(0);
            if (more)
                asm volatile("s_waitcnt vmcnt(%0)" :: "n"(LOADS) : "memory");
            else
                asm volatile("s_waitcnt vmcnt(0)" ::: "memory");
            __builtin_amdgcn_s_barrier();
        } else {
            // ---- single phase: 16 MFMA; stage A+B(t+2); counted vmcnt ----
            if (more) { STAGE_A(koff, nb); STAGE_B(koff, nb); }
            __builtin_amdgcn_s_setprio(1);
            #pragma unroll
            for (int mf = 0; mf < 4; ++mf)
                #pragma unroll
                for (int nf = 0; nf < 4; ++nf)
                    acc[mf][nf] = __builtin_amdgcn_mfma_f32_16x16x32_bf16(
                        af[mf], bfr[nf], acc[mf][nf], 0, 0, 0);
            __builtin_amdgcn_s_setprio(0);
            if (more)
                asm volatile("s_waitcnt vmcnt(%0)" :: "n"(LOADS) : "memory");
            else
                asm volatile("s_waitcnt vmcnt(0)" ::: "memory");
            __builtin_amdgcn_s_barrier();
        }
    }
    #undef STAGE_A
    #undef STAGE_B
    #undef LDA
    #undef LDB

    // epilogue: C/D layout col = lane&15, row = (lane>>4)*4 + r
    const int rbase = g * 4;
    #pragma unroll
    for (int mf = 0; mf < MF; ++mf) {
        #pragma unroll
        for (int nf = 0; nf < 4; ++nf) {
            const int col = n0 + wn + nf * 16 + l15;
            const float bcol = bias[col];
            #pragma unroll
            for (int r = 0; r < 4; ++r) {
                const int row = m0 + wm + mf * 16 + rbase + r;
                float v = acc[mf][nf][r] + bcol;
                const size_t idx = (size_t)row * N + col;
                if (MODE == 0) {
                    ((ushort_t*)Cout)[idx] = f2bf(v);
                } else if (MODE == 1) {
                    ((ushort_t*)Cout)[idx] = f2bf(fmaxf(v, 0.0f));
                } else {
                    ((float*)Cout)[idx] = res[idx] + RES_ * v;
                }
            }
        }
    }
}

// ---------------------------------------------------------------------------
// Flash attention v5 (causal) from packed qkv (bf16 [8192][3072]).
// - 64-row q-tiles, 4 waves x 16 rows; paired triangle (uniform 33 iters)
// - swapped QK^T, reg-prefetch staging (T14), exp2 softmax, defer-max (T13)
// out: bf16 [8192][1024]
// ---------------------------------------------------------------------------
__global__ __launch_bounds__(256) void fattn_kernel(
    const ushort_t* __restrict__ qkv, ushort_t* __restrict__ out)
{
    __shared__ __align__(16) ushort_t Ks[64 * 64];     // [key][d], chunk c^=key&7
    __shared__ __align__(16) ushort_t Vt[64 * 64];     // [d][key], chunk c^=(d&7)^((d>>3)&7)
    __shared__ __align__(16) ushort_t Ps[4][16 * 64];  // per-wave [q][key], 16B-chunk c16^=q&7

    const int tid  = threadIdx.x;
    const int lane = tid & 63;
    const int w    = tid >> 6;
    const int bh = blockIdx.y;
    const int b = bh >> 4, h = bh & 15;

    const int l15 = lane & 15;
    const int g   = lane >> 4;

    const size_t rs = 3 * D_;
    const ushort_t* Qg = qkv + (size_t)b * S_ * rs + h * HD_;
    const ushort_t* Kg = Qg + D_;

    // staging geometry (constant per thread)
    const int skey = tid >> 3;          // 0..31 (+32 on pass 1)
    const int sc   = tid & 7;           // 16B chunk within row

    #pragma unroll
    for (int half = 0; half < 2; ++half) {
        const int qt = half ? blockIdx.x : (S_ / 64 - 1) - blockIdx.x;
        const int q0 = qt * 64;
        const int nkb = qt + 1;

        // Q B-frags (col=q=l15, k=g*8+e +kk*32), pre-scaled by SCALE_*log2e
        bf16x8 qf[2];
        {
            const int qrow = q0 + w * 16 + l15;
            #pragma unroll
            for (int kk = 0; kk < 2; ++kk) {
                bf16x8 tq = *(const bf16x8*)(Qg + (size_t)qrow * rs + kk * 32 + g * 8);
                #pragma unroll
                for (int e = 0; e < 8; ++e)
                    tq[e] = (short)f2bf(bf2f((ushort_t)tq[e]) * (SCALE_ * LOG2E_));
                qf[kk] = tq;
            }
        }

        float mrow = -1e30f, lrow = 0.f;
        f32x4 oacc[4] = {};   // d-frags; D: col=d=l15, row(q-local)=g*4+r

        // prologue: load KV tile 0 into regs
        bf16x8 kvreg[2], vvreg[2];
        #pragma unroll
        for (int pass = 0; pass < 2; ++pass) {
            const ushort_t* src = Kg + (size_t)(pass * 32 + skey) * rs + sc * 8;
            kvreg[pass] = *(const bf16x8*)src;
            vvreg[pass] = *(const bf16x8*)(src + D_);
        }

        for (int kb = 0; kb < nkb; ++kb) {
            __syncthreads();   // prior compute done reading LDS
            // ---- write staged regs -> LDS (K swizzled b128, V^T scatter) ----
            #pragma unroll
            for (int pass = 0; pass < 2; ++pass) {
                const int key = pass * 32 + skey;
                *(bf16x8*)&Ks[key * 64 + ((sc ^ (key & 7)) << 3)] = kvreg[pass];
                #pragma unroll
                for (int j = 0; j < 8; ++j) {
                    const int d  = sc * 8 + j;
                    const int cp = (key >> 3) ^ (d & 7) ^ ((d >> 3) & 7);
                    Vt[d * 64 + (cp << 3) + (key & 7)] = (ushort_t)vvreg[pass][j];
                }
            }
            // ---- prefetch next KV tile into regs (hidden under compute) ----
            if (kb + 1 < nkb) {
                #pragma unroll
                for (int pass = 0; pass < 2; ++pass) {
                    const ushort_t* src =
                        Kg + (size_t)((kb + 1) * 64 + pass * 32 + skey) * rs + sc * 8;
                    kvreg[pass] = *(const bf16x8*)src;
                    vvreg[pass] = *(const bf16x8*)(src + D_);
                }
            }
            __syncthreads();   // staging visible

            // ---- S^T = K Q^T (D[key][q]: col=q=l15, row=key=g*4+r) ----
            f32x4 sf[4] = {};
            __builtin_amdgcn_s_setprio(1);
            #pragma unroll
            for (int kk = 0; kk < 2; ++kk) {
                const int cc = kk * 4 + g;
                #pragma unroll
                for (int nf = 0; nf < 4; ++nf) {
                    const int keyr = nf * 16 + l15;
                    bf16x8 kf = *(const bf16x8*)&Ks[keyr * 64 + ((cc ^ (keyr & 7)) << 3)];
                    sf[nf] = __builtin_amdgcn_mfma_f32_16x16x32_bf16(kf, qf[kk], sf[nf], 0, 0, 0);
                }
            }
            __builtin_amdgcn_s_setprio(0);

            // ---- mask (only last kv-block can cross the diagonal) ----
            if (kb == nkb - 1) {
                const int q = q0 + w * 16 + l15;
                #pragma unroll
                for (int nf = 0; nf < 4; ++nf)
                    #pragma unroll
                    for (int r = 0; r < 4; ++r)
                        if (kb * 64 + nf * 16 + g * 4 + r > q) sf[nf][r] = -1e30f;
            }
            // ---- per-row max ----
            float mx = -1e30f;
            #pragma unroll
            for (int nf = 0; nf < 4; ++nf)
                #pragma unroll
                for (int r = 0; r < 4; ++r) mx = fmaxf(mx, sf[nf][r]);
            mx = fmaxf(mx, __shfl_xor(mx, 16));
            mx = fmaxf(mx, __shfl_xor(mx, 32));

            // ---- deferred-max rescale (T13, THR=8 in log2 units) ----
            if (!__all(mx - mrow <= 8.0f)) {
                const float mnew = fmaxf(mrow, mx);
                const float corr = fexp2(mrow - mnew);
                mrow = mnew;
                lrow *= corr;
                #pragma unroll
                for (int r = 0; r < 4; ++r) {
                    const float cr = __shfl(corr, g * 4 + r, 16);
                    #pragma unroll
                    for (int nf = 0; nf < 4; ++nf) oacc[nf][r] *= cr;
                }
            }

            // ---- P = exp2(S - m), row-sum, packed write to Ps ----
            {
                const int qrow = l15;
                float psum = 0.f;
                #pragma unroll
                for (int nf = 0; nf < 4; ++nf) {
                    const float p0 = fexp2(sf[nf][0] - mrow);
                    const float p1 = fexp2(sf[nf][1] - mrow);
                    const float p2 = fexp2(sf[nf][2] - mrow);
                    const float p3 = fexp2(sf[nf][3] - mrow);
                    psum += (p0 + p1) + (p2 + p3);
                    uint2 pk = make_uint2(cvt_pk_bf16(p0, p1), cvt_pk_bf16(p2, p3));
                    const int c16 = ((nf << 1) + (g >> 1)) ^ (qrow & 7);
                    *(uint2*)((char*)Ps[w] + qrow * 128 + c16 * 16 + (g & 1) * 8) = pk;
                }
                psum += __shfl_xor(psum, 16);
                psum += __shfl_xor(psum, 32);
                lrow += psum;
            }

            // ---- O += P V (A=P from Ps, B=V^T from Vt) ----
            #pragma unroll
            for (int kk = 0; kk < 2; ++kk) {
                const int cc = kk * 4 + g;
                const int qrow = l15;
                const int c16 = cc ^ (qrow & 7);
                bf16x8 pa = *(const bf16x8*)((const char*)Ps[w] + qrow * 128 + c16 * 16);
                __builtin_amdgcn_s_setprio(1);
                #pragma unroll
                for (int nf = 0; nf < 4; ++nf) {
                    const int dr  = nf * 16 + l15;
                    const int cvp = cc ^ (dr & 7) ^ ((dr >> 3) & 7);
                    bf16x8 vf = *(const bf16x8*)&Vt[dr * 64 + (cvp << 3)];
                    oacc[nf] = __builtin_amdgcn_mfma_f32_16x16x32_bf16(pa, vf, oacc[nf], 0, 0, 0);
                }
                __builtin_amdgcn_s_setprio(0);
            }
        }

        // ---- epilogue: O = acc / l (l lives at lane l15=row; broadcast) ----
        const float linv = 1.0f / lrow;
        #pragma unroll
        for (int r = 0; r < 4; ++r) {
            const float li = __shfl(linv, g * 4 + r, 16);
            const int q = q0 + w * 16 + g * 4 + r;
            ushort_t* op = out + (size_t)(b * S_ + q) * D_ + h * HD_;
            #pragma unroll
            for (int nf = 0; nf < 4; ++nf)
                op[nf * 16 + l15] = f2bf(oacc[nf][r] * li);
        }
    }
}

// ---------------------------------------------------------------------------
// launch
// ---------------------------------------------------------------------------
extern "C" void kernel_launch(void* const* d_in, const int* in_sizes, int n_in,
                              void* d_out, int out_size, void* d_ws, size_t ws_size,
                              hipStream_t stream)
{
    const float* x   = (const float*)d_in[0];
    const float* Wq  = (const float*)d_in[1];
    const float* bq  = (const float*)d_in[2];
    const float* Wk  = (const float*)d_in[3];
    const float* bk  = (const float*)d_in[4];
    const float* Wv  = (const float*)d_in[5];
    const float* bv  = (const float*)d_in[6];
    const float* Wo  = (const float*)d_in[7];
    const float* bo  = (const float*)d_in[8];
    const float* g1  = (const float*)d_in[9];
    const float* be1 = (const float*)d_in[10];
    const float* g2  = (const float*)d_in[11];
    const float* be2 = (const float*)d_in[12];
    const float* W1  = (const float*)d_in[13];
    const float* b1  = (const float*)d_in[14];
    const float* W2  = (const float*)d_in[15];
    const float* b2  = (const float*)d_in[16];
    float* out = (float*)d_out;

    char* ws = (char*)d_ws;
    size_t o = 0;
    auto alloc = [&](size_t bytes) { size_t r = o; o = (o + bytes + 255) & ~(size_t)255; return r; };
    ushort_t* Wqkvt = (ushort_t*)(ws + alloc((size_t)3 * D_ * D_ * 2));   // [3072][1024]
    ushort_t* Wot   = (ushort_t*)(ws + alloc((size_t)D_ * D_ * 2));      // [1024][1024]
    ushort_t* W1t   = (ushort_t*)(ws + alloc((size_t)DFF_ * D_ * 2));    // [4096][1024]
    ushort_t* W2t   = (ushort_t*)(ws + alloc((size_t)D_ * DFF_ * 2));    // [1024][4096]
    float*    bqkv  = (float*)(ws + alloc((size_t)3 * D_ * 4));
    ushort_t* lnbuf = (ushort_t*)(ws + alloc((size_t)M_ * D_ * 2));      // ln1 then ln2
    ushort_t* bigbuf= (ushort_t*)(ws + alloc((size_t)M_ * DFF_ * 2));    // qkv then ffn-hidden
    ushort_t* attnb = (ushort_t*)(ws + alloc((size_t)M_ * D_ * 2));
    float*    x1    = (float*)(ws + alloc((size_t)M_ * D_ * 4));

    dim3 tblock(32, 8);
    transpose_cast_kernel<<<dim3(D_/32, D_/32), tblock, 0, stream>>>(Wq, Wqkvt,            D_, D_);
    transpose_cast_kernel<<<dim3(D_/32, D_/32), tblock, 0, stream>>>(Wk, Wqkvt + D_*D_,    D_, D_);
    transpose_cast_kernel<<<dim3(D_/32, D_/32), tblock, 0, stream>>>(Wv, Wqkvt + 2*D_*D_,  D_, D_);
    transpose_cast_kernel<<<dim3(D_/32, D_/32), tblock, 0, stream>>>(Wo, Wot,              D_, D_);
    transpose_cast_kernel<<<dim3(DFF_/32, D_/32), tblock, 0, stream>>>(W1, W1t,            D_, DFF_);
    transpose_cast_kernel<<<dim3(D_/32, DFF_/32), tblock, 0, stream>>>(W2, W2t,            DFF_, D_);
    concat_bias_kernel<<<12, 256, 0, stream>>>(bq, bk, bv, bqkv);

    // ln1
    ln_kernel<<<M_, 256, 0, stream>>>(x, g1, be1, lnbuf);
    // qkv = ln1 @ Wqkv + bqkv          [8192][3072] bf16   grid 32*12=384
    gemmT_kernel<0, 256><<<(M_/256)*(3*D_/256), 512, 0, stream>>>(
        lnbuf, Wqkvt, bqkv, nullptr, bigbuf, M_, 3*D_, D_, 3*D_/256);
    // flash attention (paired q-tiles)  [8192][1024] bf16
    fattn_kernel<<<dim3(S_/128, B_*H_), 256, 0, stream>>>(bigbuf, attnb);
    // x1 = x + RES*(attn @ Wo + bo)     [8192][1024] fp32  grid 64*4=256
    gemmT_kernel<2, 128><<<(M_/128)*(D_/256), 512, 0, stream>>>(
        attnb, Wot, bo, x, x1, M_, D_, D_, D_/256);
    // ln2
    ln_kernel<<<M_, 256, 0, stream>>>(x1, g2, be2, lnbuf);
    // ffh = relu(ln2 @ W1 + b1)         [8192][4096] bf16  grid 32*16=512
    gemmT_kernel<1, 256><<<(M_/256)*(DFF_/256), 512, 0, stream>>>(
        lnbuf, W1t, b1, nullptr, bigbuf, M_, DFF_, D_, DFF_/256);
    // out = x1 + RES*(ffh @ W2 + b2)    [8192][1024] fp32  grid 64*4=256
    gemmT_kernel<2, 128><<<(M_/128)*(D_/256), 512, 0, stream>>>(
        bigbuf, W2t, b2, x1, out, M_, D_, DFF_, D_/256);
}

// Round 11
// 382.881 us; speedup vs baseline: 1.2585x; 1.0139x over previous
//
#include <hip/hip_runtime.h>

typedef unsigned short ushort_t;
typedef unsigned int uint32;
typedef __attribute__((ext_vector_type(4))) float f32x4;
typedef __attribute__((ext_vector_type(8))) short bf16x8;

#define B_   4
#define S_   2048
#define D_   1024
#define H_   16
#define HD_  64
#define DFF_ 4096
#define M_   (B_ * S_)          // 8192 rows (tokens)

#define RES_   0.28867513459481287f   // 1/sqrt(12)
#define SCALE_ 0.03125f               // 1/sqrt(1024)
#define EPS_   1e-5f
#define LOG2E_ 1.4426950408889634f

__device__ __forceinline__ ushort_t f2bf(float f) {
    union { float f; uint32 u; } c; c.f = f;
    uint32 u = c.u + 0x7fffu + ((c.u >> 16) & 1u);
    return (ushort_t)(u >> 16);
}
__device__ __forceinline__ float bf2f(ushort_t h) {
    union { uint32 u; float f; } c; c.u = ((uint32)h) << 16;
    return c.f;
}
__device__ __forceinline__ float fexp2(float x) {
    float r; asm("v_exp_f32 %0, %1" : "=v"(r) : "v"(x)); return r;
}
__device__ __forceinline__ uint32 cvt_pk_bf16(float lo, float hi) {
    uint32 r;
    asm("v_cvt_pk_bf16_f32 %0, %1, %2" : "=v"(r) : "v"(lo), "v"(hi));
    return r;
}

#define GLDS(src_, dst_)                                                     \
    __builtin_amdgcn_global_load_lds(                                        \
        (const __attribute__((address_space(1))) void*)(src_),               \
        (__attribute__((address_space(3))) void*)(dst_), 16, 0, 0)

// ---------------------------------------------------------------------------
// Transpose + fp32->bf16 cast:  W[K][N] (fp32, row-major) -> Wt[N][K] (bf16)
// ---------------------------------------------------------------------------
__global__ __launch_bounds__(256) void transpose_cast_kernel(
    const float* __restrict__ W, ushort_t* __restrict__ Wt, int K, int N)
{
    __shared__ float tile[32][33];
    const int bx = blockIdx.x * 32;  // N offset
    const int by = blockIdx.y * 32;  // K offset
    const int tx = threadIdx.x;      // 0..31
    const int ty = threadIdx.y;      // 0..7
    #pragma unroll
    for (int i = 0; i < 32; i += 8)
        tile[ty + i][tx] = W[(size_t)(by + ty + i) * N + bx + tx];
    __syncthreads();
    #pragma unroll
    for (int i = 0; i < 32; i += 8)
        Wt[(size_t)(bx + ty + i) * K + by + tx] = f2bf(tile[tx][ty + i]);
}

// ---------------------------------------------------------------------------
// Concat bq,bk,bv -> bqkv[3072]
// ---------------------------------------------------------------------------
__global__ void concat_bias_kernel(const float* __restrict__ bq,
                                   const float* __restrict__ bk,
                                   const float* __restrict__ bv,
                                   float* __restrict__ bqkv)
{
    int i = blockIdx.x * blockDim.x + threadIdx.x;
    if (i < 3 * D_) {
        float v = (i < D_) ? bq[i] : (i < 2 * D_) ? bk[i - D_] : bv[i - 2 * D_];
        bqkv[i] = v;
    }
}

// ---------------------------------------------------------------------------
// LayerNorm: fp32 in [rows][1024] -> bf16 out
// ---------------------------------------------------------------------------
__global__ __launch_bounds__(256) void ln_kernel(
    const float* __restrict__ x, const float* __restrict__ g,
    const float* __restrict__ be, ushort_t* __restrict__ out)
{
    const int row = blockIdx.x;
    const int t = threadIdx.x;
    const int lane = t & 63;
    const int wave = t >> 6;
    const float4* xr = (const float4*)(x + (size_t)row * D_);
    float4 v = xr[t];
    float s  = v.x + v.y + v.z + v.w;
    float s2 = v.x * v.x + v.y * v.y + v.z * v.z + v.w * v.w;
    #pragma unroll
    for (int off = 32; off; off >>= 1) {
        s  += __shfl_xor(s, off);
        s2 += __shfl_xor(s2, off);
    }
    __shared__ float red[8];
    if (lane == 0) { red[wave * 2] = s; red[wave * 2 + 1] = s2; }
    __syncthreads();
    s  = red[0] + red[2] + red[4] + red[6];
    s2 = red[1] + red[3] + red[5] + red[7];
    const float mean = s * (1.0f / D_);
    const float var  = s2 * (1.0f / D_) - mean * mean;
    const float rstd = rsqrtf(var + EPS_);
    const float4 gv  = ((const float4*)g)[t];
    const float4 bv  = ((const float4*)be)[t];
    ushort_t o[4];
    o[0] = f2bf((v.x - mean) * rstd * gv.x + bv.x);
    o[1] = f2bf((v.y - mean) * rstd * gv.y + bv.y);
    o[2] = f2bf((v.z - mean) * rstd * gv.z + bv.z);
    o[3] = f2bf((v.w - mean) * rstd * gv.w + bv.w);
    *(ushort2*)&out[(size_t)row * D_ + t * 4]     = make_ushort2(o[0], o[1]);
    *(ushort2*)&out[(size_t)row * D_ + t * 4 + 2] = make_ushort2(o[2], o[3]);
}

// ---------------------------------------------------------------------------
// GEMM v8: C[M][N] = epilogue(A[M][K] @ Bt[N][K]^T + bias)
// Structure = R9's gemmT (verified win).
// MODE 0: bf16 out.  MODE 1: relu bf16.  MODE 2: fp32 res + RES*(.).
// MODE 3: qkv — cols <2048 (Q,K) as MODE 0 into Cout; cols >=2048 (V)
//         written TRANSPOSED into vt as [b][h][hd][s] (pack-4 along s).
// ---------------------------------------------------------------------------
template <int MODE, int BM>
__global__ __launch_bounds__(512, (BM == 256) ? 1 : 2) void gemmT_kernel(
    const ushort_t* __restrict__ A, const ushort_t* __restrict__ Bt,
    const float* __restrict__ bias, const float* __restrict__ res,
    void* __restrict__ Cout, ushort_t* __restrict__ vt,
    int M, int N, int K, int gx)
{
    constexpr int MF     = BM / 32;        // m-frags per wave (8 or 4)
    constexpr int ALOADS = BM / 128;       // A gloads per thread (2 or 1)
    constexpr int LOADS  = ALOADS + 2;     // gloads per K-tile per thread

    __shared__ __align__(16) ushort_t As[3][BM * 32];
    __shared__ __align__(16) ushort_t Bs[3][256 * 32];

    const int tid  = threadIdx.x;
    const int w    = tid >> 6;
    const int lane = tid & 63;
    const int l15  = lane & 15;
    const int g    = lane >> 4;

    // T1: bijective XCD swizzle (gridDim.x % 8 == 0)
    const int cpx = gridDim.x >> 3;
    const int swz = (blockIdx.x & 7) * cpx + (blockIdx.x >> 3);
    const int bx = swz % gx, by = swz / gx;
    const int m0 = by * BM, n0 = bx * 256;

    const int wm = (w >> 2) * (BM / 2);    // 2 M-waves
    const int wn = (w & 3) * 64;           // 4 N-waves

    const ushort_t* srcA[ALOADS];
    int ldsA[ALOADS];
    const ushort_t* srcB[2];
    int ldsB[2];
    #pragma unroll
    for (int p = 0; p < ALOADS; ++p) {
        const int L = p * 512 + tid;
        const int row = L >> 2;
        srcA[p] = A + (size_t)(m0 + row) * K + (((L & 3) ^ ((row >> 1) & 3)) << 3);
        ldsA[p] = (p * 512 + w * 64) * 8;      // wave-uniform; HW adds lane*16B
    }
    #pragma unroll
    for (int p = 0; p < 2; ++p) {
        const int L = p * 512 + tid;
        const int row = L >> 2;
        srcB[p] = Bt + (size_t)(n0 + row) * K + (((L & 3) ^ ((row >> 1) & 3)) << 3);
        ldsB[p] = (p * 512 + w * 64) * 8;
    }

    #define STAGE_A(koff_, buf_)                                             \
        do { _Pragma("unroll")                                               \
             for (int p = 0; p < ALOADS; ++p)                                \
                 GLDS(srcA[p] + (koff_), &As[buf_][ldsA[p]]); } while (0)
    #define STAGE_B(koff_, buf_)                                             \
        do { _Pragma("unroll")                                               \
             for (int p = 0; p < 2; ++p)                                     \
                 GLDS(srcB[p] + (koff_), &Bs[buf_][ldsB[p]]); } while (0)

    #define LDA(mf_) (*(const bf16x8*)&As[cur][(wm + (mf_) * 16 + l15) * 32 + \
                        ((g ^ (((wm + (mf_) * 16 + l15) >> 1) & 3)) << 3)])
    #define LDB(nf_) (*(const bf16x8*)&Bs[cur][(wn + (nf_) * 16 + l15) * 32 + \
                        ((g ^ (((wn + (nf_) * 16 + l15) >> 1) & 3)) << 3)])

    f32x4 acc[MF][4] = {};
    const int NT = K >> 5;

    STAGE_A(0, 0); STAGE_B(0, 0);
    STAGE_A(32, 1); STAGE_B(32, 1);
    asm volatile("s_waitcnt vmcnt(%0)" :: "n"(LOADS) : "memory");  // tile0 in
    __builtin_amdgcn_s_barrier();

    for (int t = 0; t < NT; ++t) {
        const int cur = t % 3;
        const int nb  = (t + 2) % 3;
        const bool more = (t + 2 < NT);
        const size_t koff = (size_t)(t + 2) * 32;

        bf16x8 af[4], bfr[4];
        #pragma unroll
        for (int nf = 0; nf < 4; ++nf) bfr[nf] = LDB(nf);
        #pragma unroll
        for (int mf = 0; mf < 4; ++mf) af[mf] = LDA(mf);

        if (BM == 256) {
            if (more) STAGE_A(koff, nb);
            __builtin_amdgcn_s_barrier();
            __builtin_amdgcn_s_setprio(1);
            #pragma unroll
            for (int mf = 0; mf < 4; ++mf)
                #pragma unroll
                for (int nf = 0; nf < 4; ++nf)
                    acc[mf][nf] = __builtin_amdgcn_mfma_f32_16x16x32_bf16(
                        af[mf], bfr[nf], acc[mf][nf], 0, 0, 0);
            __builtin_amdgcn_s_setprio(0);
            __builtin_amdgcn_s_barrier();

            #pragma unroll
            for (int mf = 0; mf < 4; ++mf) af[mf] = LDA(mf + 4);
            if (more) STAGE_B(koff, nb);
            __builtin_amdgcn_s_barrier();
            __builtin_amdgcn_s_setprio(1);
            #pragma unroll
            for (int mf = 0; mf < 4; ++mf)
                #pragma unroll
                for (int nf = 0; nf < 4; ++nf)
                    acc[(MF == 8 ? mf + 4 : mf)][nf] =
                        __builtin_amdgcn_mfma_f32_16x16x32_bf16(
                            af[mf], bfr[nf], acc[(MF == 8 ? mf + 4 : mf)][nf], 0, 0, 0);
            __builtin_amdgcn_s_setprio(0);
            if (more)
                asm volatile("s_waitcnt vmcnt(%0)" :: "n"(LOADS) : "memory");
            else
                asm volatile("s_waitcnt vmcnt(0)" ::: "memory");
            __builtin_amdgcn_s_barrier();
        } else {
            if (more) { STAGE_A(koff, nb); STAGE_B(koff, nb); }
            __builtin_amdgcn_s_setprio(1);
            #pragma unroll
            for (int mf = 0; mf < 4; ++mf)
                #pragma unroll
                for (int nf = 0; nf < 4; ++nf)
                    acc[mf][nf] = __builtin_amdgcn_mfma_f32_16x16x32_bf16(
                        af[mf], bfr[nf], acc[mf][nf], 0, 0, 0);
            __builtin_amdgcn_s_setprio(0);
            if (more)
                asm volatile("s_waitcnt vmcnt(%0)" :: "n"(LOADS) : "memory");
            else
                asm volatile("s_waitcnt vmcnt(0)" ::: "memory");
            __builtin_amdgcn_s_barrier();
        }
    }
    #undef STAGE_A
    #undef STAGE_B
    #undef LDA
    #undef LDB

    // epilogue: C/D layout col = lane&15, row = (lane>>4)*4 + r
    const int rbase = g * 4;
    const bool isV = (MODE == 3) && (n0 >= 2 * D_);
    #pragma unroll
    for (int mf = 0; mf < MF; ++mf) {
        #pragma unroll
        for (int nf = 0; nf < 4; ++nf) {
            const int col = n0 + wn + nf * 16 + l15;
            const float bcol = bias[col];
            if (isV) {
                // V block: write transposed to vt[b][h][hd][s], pack-4 along s
                const int d  = col - 2 * D_;
                const int b  = m0 >> 11;                        // tile within one batch
                const int sb = (m0 + wm + mf * 16 + rbase) & (S_ - 1);
                ushort4 pk = make_ushort4(
                    f2bf(acc[mf][nf][0] + bcol), f2bf(acc[mf][nf][1] + bcol),
                    f2bf(acc[mf][nf][2] + bcol), f2bf(acc[mf][nf][3] + bcol));
                *(ushort4*)&vt[(((size_t)(b * H_ + (d >> 6)) * HD_) + (d & 63)) * S_ + sb] = pk;
            } else {
                #pragma unroll
                for (int r = 0; r < 4; ++r) {
                    const int row = m0 + wm + mf * 16 + rbase + r;
                    float v = acc[mf][nf][r] + bcol;
                    const size_t idx = (size_t)row * N + col;
                    if (MODE == 0 || MODE == 3) {
                        ((ushort_t*)Cout)[idx] = f2bf(v);
                    } else if (MODE == 1) {
                        ((ushort_t*)Cout)[idx] = f2bf(fmaxf(v, 0.0f));
                    } else {
                        ((float*)Cout)[idx] = res[idx] + RES_ * v;
                    }
                }
            }
        }
    }
}

// ---------------------------------------------------------------------------
// Flash attention v6 (causal). Q,K from packed qkv (bf16 [8192][3072]);
// V from pre-transposed vt [b][h][hd][s] (bf16).
// - 64-row q-tiles, 4 waves x 16 rows; paired triangle (uniform 33 iters)
// - bh-coherent XCD mapping: lin = x*64 + bh -> lin%8 == bh%8, so each XCD
//   caches only 8 bh's KV (4MB = L2)
// - V^T staged with vectorized b128 (no scatter); swapped QK^T; exp2 softmax;
//   defer-max (T13); reg-prefetch (T14)
// out: bf16 [8192][1024]
// ---------------------------------------------------------------------------
__global__ __launch_bounds__(256) void fattn_kernel(
    const ushort_t* __restrict__ qkv, const ushort_t* __restrict__ vtg,
    ushort_t* __restrict__ out)
{
    __shared__ __align__(16) ushort_t Ks[64 * 64];     // [key][d], chunk c^=key&7
    __shared__ __align__(16) ushort_t Vt[64 * 64];     // [d][key], chunk c^=d&7
    __shared__ __align__(16) ushort_t Ps[4][16 * 64];  // per-wave [q][key]

    const int tid  = threadIdx.x;
    const int lane = tid & 63;
    const int w    = tid >> 6;
    const int lin  = blockIdx.x;
    const int xi   = lin >> 6;          // 0..15 : q-tile pair index
    const int bh   = lin & 63;          // lin%8 == bh%8 -> XCD-coherent
    const int b = bh >> 4, h = bh & 15;

    const int l15 = lane & 15;
    const int g   = lane >> 4;

    const size_t rs = 3 * D_;
    const ushort_t* Qg = qkv + (size_t)b * S_ * rs + h * HD_;
    const ushort_t* Kg = Qg + D_;
    const ushort_t* Vg = vtg + (size_t)bh * HD_ * S_;   // [hd][s]

    // staging geometry: idx = pass*256+tid; row = idx>>3 (key or d), c = idx&7
    const int srow = tid >> 3;          // 0..31 (+32 on pass 1)
    const int sc   = tid & 7;

    #pragma unroll
    for (int half = 0; half < 2; ++half) {
        const int qt = half ? xi : (S_ / 64 - 1) - xi;
        const int q0 = qt * 64;
        const int nkb = qt + 1;

        // Q B-frags (col=q=l15, k=g*8+e +kk*32), pre-scaled by SCALE_*log2e
        bf16x8 qf[2];
        {
            const int qrow = q0 + w * 16 + l15;
            #pragma unroll
            for (int kk = 0; kk < 2; ++kk) {
                bf16x8 tq = *(const bf16x8*)(Qg + (size_t)qrow * rs + kk * 32 + g * 8);
                #pragma unroll
                for (int e = 0; e < 8; ++e)
                    tq[e] = (short)f2bf(bf2f((ushort_t)tq[e]) * (SCALE_ * LOG2E_));
                qf[kk] = tq;
            }
        }

        float mrow = -1e30f, lrow = 0.f;
        f32x4 oacc[4] = {};   // d-frags; D: col=d=l15, row(q-local)=g*4+r

        // prologue: load KV tile 0 into regs
        bf16x8 kvreg[2], vvreg[2];
        #pragma unroll
        for (int pass = 0; pass < 2; ++pass) {
            const int row = pass * 32 + srow;
            kvreg[pass] = *(const bf16x8*)(Kg + (size_t)row * rs + sc * 8);
            vvreg[pass] = *(const bf16x8*)(Vg + (size_t)row * S_ + sc * 8);
        }

        for (int kb = 0; kb < nkb; ++kb) {
            __syncthreads();   // prior compute done reading LDS
            // ---- write staged regs -> LDS (both b128, swizzled) ----
            #pragma unroll
            for (int pass = 0; pass < 2; ++pass) {
                const int row = pass * 32 + srow;
                *(bf16x8*)&Ks[row * 64 + ((sc ^ (row & 7)) << 3)] = kvreg[pass];
                *(bf16x8*)&Vt[row * 64 + ((sc ^ (row & 7)) << 3)] = vvreg[pass];
            }
            // ---- prefetch next KV tile into regs (hidden under compute) ----
            if (kb + 1 < nkb) {
                #pragma unroll
                for (int pass = 0; pass < 2; ++pass) {
                    const int row = pass * 32 + srow;
                    kvreg[pass] = *(const bf16x8*)(
                        Kg + (size_t)((kb + 1) * 64 + row) * rs + sc * 8);
                    vvreg[pass] = *(const bf16x8*)(
                        Vg + (size_t)row * S_ + (kb + 1) * 64 + sc * 8);
                }
            }
            __syncthreads();   // staging visible

            // ---- S^T = K Q^T (D[key][q]: col=q=l15, row=key=g*4+r) ----
            f32x4 sf[4] = {};
            __builtin_amdgcn_s_setprio(1);
            #pragma unroll
            for (int kk = 0; kk < 2; ++kk) {
                const int cc = kk * 4 + g;
                #pragma unroll
                for (int nf = 0; nf < 4; ++nf) {
                    const int keyr = nf * 16 + l15;
                    bf16x8 kf = *(const bf16x8*)&Ks[keyr * 64 + ((cc ^ (keyr & 7)) << 3)];
                    sf[nf] = __builtin_amdgcn_mfma_f32_16x16x32_bf16(kf, qf[kk], sf[nf], 0, 0, 0);
                }
            }
            __builtin_amdgcn_s_setprio(0);

            // ---- mask (only last kv-block can cross the diagonal) ----
            if (kb == nkb - 1) {
                const int q = q0 + w * 16 + l15;
                #pragma unroll
                for (int nf = 0; nf < 4; ++nf)
                    #pragma unroll
                    for (int r = 0; r < 4; ++r)
                        if (kb * 64 + nf * 16 + g * 4 + r > q) sf[nf][r] = -1e30f;
            }
            // ---- per-row max ----
            float mx = -1e30f;
            #pragma unroll
            for (int nf = 0; nf < 4; ++nf)
                #pragma unroll
                for (int r = 0; r < 4; ++r) mx = fmaxf(mx, sf[nf][r]);
            mx = fmaxf(mx, __shfl_xor(mx, 16));
            mx = fmaxf(mx, __shfl_xor(mx, 32));

            // ---- deferred-max rescale (T13, THR=8 in log2 units) ----
            if (!__all(mx - mrow <= 8.0f)) {
                const float mnew = fmaxf(mrow, mx);
                const float corr = fexp2(mrow - mnew);
                mrow = mnew;
                lrow *= corr;
                #pragma unroll
                for (int r = 0; r < 4; ++r) {
                    const float cr = __shfl(corr, g * 4 + r, 16);
                    #pragma unroll
                    for (int nf = 0; nf < 4; ++nf) oacc[nf][r] *= cr;
                }
            }

            // ---- P = exp2(S - m), row-sum, packed write to Ps ----
            {
                const int qrow = l15;
                float psum = 0.f;
                #pragma unroll
                for (int nf = 0; nf < 4; ++nf) {
                    const float p0 = fexp2(sf[nf][0] - mrow);
                    const float p1 = fexp2(sf[nf][1] - mrow);
                    const float p2 = fexp2(sf[nf][2] - mrow);
                    const float p3 = fexp2(sf[nf][3] - mrow);
                    psum += (p0 + p1) + (p2 + p3);
                    uint2 pk = make_uint2(cvt_pk_bf16(p0, p1), cvt_pk_bf16(p2, p3));
                    const int c16 = ((nf << 1) + (g >> 1)) ^ (qrow & 7);
                    *(uint2*)((char*)Ps[w] + qrow * 128 + c16 * 16 + (g & 1) * 8) = pk;
                }
                psum += __shfl_xor(psum, 16);
                psum += __shfl_xor(psum, 32);
                lrow += psum;
            }

            // ---- O += P V (A=P from Ps, B=V^T from Vt) ----
            #pragma unroll
            for (int kk = 0; kk < 2; ++kk) {
                const int cc = kk * 4 + g;
                const int qrow = l15;
                const int c16 = cc ^ (qrow & 7);
                bf16x8 pa = *(const bf16x8*)((const char*)Ps[w] + qrow * 128 + c16 * 16);
                __builtin_amdgcn_s_setprio(1);
                #pragma unroll
                for (int nf = 0; nf < 4; ++nf) {
                    const int dr = nf * 16 + l15;
                    bf16x8 vf = *(const bf16x8*)&Vt[dr * 64 + ((cc ^ (dr & 7)) << 3)];
                    oacc[nf] = __builtin_amdgcn_mfma_f32_16x16x32_bf16(pa, vf, oacc[nf], 0, 0, 0);
                }
                __builtin_amdgcn_s_setprio(0);
            }
        }

        // ---- epilogue: O = acc / l (l lives at lane l15=row; broadcast) ----
        const float linv = 1.0f / lrow;
        #pragma unroll
        for (int r = 0; r < 4; ++r) {
            const float li = __shfl(linv, g * 4 + r, 16);
            const int q = q0 + w * 16 + g * 4 + r;
            ushort_t* op = out + (size_t)(b * S_ + q) * D_ + h * HD_;
            #pragma unroll
            for (int nf = 0; nf < 4; ++nf)
                op[nf * 16 + l15] = f2bf(oacc[nf][r] * li);
        }
    }
}

// ---------------------------------------------------------------------------
// launch
// ---------------------------------------------------------------------------
extern "C" void kernel_launch(void* const* d_in, const int* in_sizes, int n_in,
                              void* d_out, int out_size, void* d_ws, size_t ws_size,
                              hipStream_t stream)
{
    const float* x   = (const float*)d_in[0];
    const float* Wq  = (const float*)d_in[1];
    const float* bq  = (const float*)d_in[2];
    const float* Wk  = (const float*)d_in[3];
    const float* bk  = (const float*)d_in[4];
    const float* Wv  = (const float*)d_in[5];
    const float* bv  = (const float*)d_in[6];
    const float* Wo  = (const float*)d_in[7];
    const float* bo  = (const float*)d_in[8];
    const float* g1  = (const float*)d_in[9];
    const float* be1 = (const float*)d_in[10];
    const float* g2  = (const float*)d_in[11];
    const float* be2 = (const float*)d_in[12];
    const float* W1  = (const float*)d_in[13];
    const float* b1  = (const float*)d_in[14];
    const float* W2  = (const float*)d_in[15];
    const float* b2  = (const float*)d_in[16];
    float* out = (float*)d_out;

    char* ws = (char*)d_ws;
    size_t o = 0;
    auto alloc = [&](size_t bytes) { size_t r = o; o = (o + bytes + 255) & ~(size_t)255; return r; };
    ushort_t* Wqkvt = (ushort_t*)(ws + alloc((size_t)3 * D_ * D_ * 2));   // [3072][1024]
    ushort_t* Wot   = (ushort_t*)(ws + alloc((size_t)D_ * D_ * 2));      // [1024][1024]
    ushort_t* W1t   = (ushort_t*)(ws + alloc((size_t)DFF_ * D_ * 2));    // [4096][1024]
    ushort_t* W2t   = (ushort_t*)(ws + alloc((size_t)D_ * DFF_ * 2));    // [1024][4096]
    float*    bqkv  = (float*)(ws + alloc((size_t)3 * D_ * 4));
    ushort_t* lnbuf = (ushort_t*)(ws + alloc((size_t)M_ * D_ * 2));      // ln1 then ln2
    ushort_t* bigbuf= (ushort_t*)(ws + alloc((size_t)M_ * DFF_ * 2));    // qkv then ffn-hidden
    ushort_t* attnb = (ushort_t*)(ws + alloc((size_t)M_ * D_ * 2));
    float*    x1    = (float*)(ws + alloc((size_t)M_ * D_ * 4));
    ushort_t* vtbuf = (ushort_t*)(ws + alloc((size_t)M_ * D_ * 2));      // V^T [b][h][hd][s]

    dim3 tblock(32, 8);
    transpose_cast_kernel<<<dim3(D_/32, D_/32), tblock, 0, stream>>>(Wq, Wqkvt,            D_, D_);
    transpose_cast_kernel<<<dim3(D_/32, D_/32), tblock, 0, stream>>>(Wk, Wqkvt + D_*D_,    D_, D_);
    transpose_cast_kernel<<<dim3(D_/32, D_/32), tblock, 0, stream>>>(Wv, Wqkvt + 2*D_*D_,  D_, D_);
    transpose_cast_kernel<<<dim3(D_/32, D_/32), tblock, 0, stream>>>(Wo, Wot,              D_, D_);
    transpose_cast_kernel<<<dim3(DFF_/32, D_/32), tblock, 0, stream>>>(W1, W1t,            D_, DFF_);
    transpose_cast_kernel<<<dim3(D_/32, DFF_/32), tblock, 0, stream>>>(W2, W2t,            DFF_, D_);
    concat_bias_kernel<<<12, 256, 0, stream>>>(bq, bk, bv, bqkv);

    // ln1
    ln_kernel<<<M_, 256, 0, stream>>>(x, g1, be1, lnbuf);
    // qkv = ln1 @ Wqkv + bqkv; V written transposed to vtbuf   grid 32*12=384
    gemmT_kernel<3, 256><<<(M_/256)*(3*D_/256), 512, 0, stream>>>(
        lnbuf, Wqkvt, bqkv, nullptr, bigbuf, vtbuf, M_, 3*D_, D_, 3*D_/256);
    // flash attention (paired q-tiles, bh-coherent XCD map)  [8192][1024] bf16
    fattn_kernel<<<(S_/128) * 64, 256, 0, stream>>>(bigbuf, vtbuf, attnb);
    // x1 = x + RES*(attn @ Wo + bo)     [8192][1024] fp32  grid 64*4=256
    gemmT_kernel<2, 128><<<(M_/128)*(D_/256), 512, 0, stream>>>(
        attnb, Wot, bo, x, x1, nullptr, M_, D_, D_, D_/256);
    // ln2
    ln_kernel<<<M_, 256, 0, stream>>>(x1, g2, be2, lnbuf);
    // ffh = relu(ln2 @ W1 + b1)         [8192][4096] bf16  grid 32*16=512
    gemmT_kernel<1, 256><<<(M_/256)*(DFF_/256), 512, 0, stream>>>(
        lnbuf, W1t, b1, nullptr, bigbuf, nullptr, M_, DFF_, D_, DFF_/256);
    // out = x1 + RES*(ffh @ W2 + b2)    [8192][1024] fp32  grid 64*4=256
    gemmT_kernel<2, 128><<<(M_/128)*(D_/256), 512, 0, stream>>>(
        bigbuf, W2t, b2, x1, out, nullptr, M_, D_, DFF_, D_/256);
}

// Round 12
// 381.448 us; speedup vs baseline: 1.2632x; 1.0038x over previous
//
#include <hip/hip_runtime.h>

typedef unsigned short ushort_t;
typedef unsigned int uint32;
typedef __attribute__((ext_vector_type(4))) float f32x4;
typedef __attribute__((ext_vector_type(8))) short bf16x8;

#define B_   4
#define S_   2048
#define D_   1024
#define H_   16
#define HD_  64
#define DFF_ 4096
#define M_   (B_ * S_)          // 8192 rows (tokens)

#define RES_   0.28867513459481287f   // 1/sqrt(12)
#define SCALE_ 0.03125f               // 1/sqrt(1024)
#define EPS_   1e-5f
#define LOG2E_ 1.4426950408889634f

__device__ __forceinline__ ushort_t f2bf(float f) {
    union { float f; uint32 u; } c; c.f = f;
    uint32 u = c.u + 0x7fffu + ((c.u >> 16) & 1u);
    return (ushort_t)(u >> 16);
}
__device__ __forceinline__ float bf2f(ushort_t h) {
    union { uint32 u; float f; } c; c.u = ((uint32)h) << 16;
    return c.f;
}
__device__ __forceinline__ float fexp2(float x) {
    float r; asm("v_exp_f32 %0, %1" : "=v"(r) : "v"(x)); return r;
}
__device__ __forceinline__ uint32 cvt_pk_bf16(float lo, float hi) {
    uint32 r;
    asm("v_cvt_pk_bf16_f32 %0, %1, %2" : "=v"(r) : "v"(lo), "v"(hi));
    return r;
}

#define GLDS(src_, dst_)                                                     \
    __builtin_amdgcn_global_load_lds(                                        \
        (const __attribute__((address_space(1))) void*)(src_),               \
        (__attribute__((address_space(3))) void*)(dst_), 16, 0, 0)

// ---------------------------------------------------------------------------
// Transpose + fp32->bf16 cast:  W[K][N] (fp32, row-major) -> Wt[N][K] (bf16)
// ---------------------------------------------------------------------------
__global__ __launch_bounds__(256) void transpose_cast_kernel(
    const float* __restrict__ W, ushort_t* __restrict__ Wt, int K, int N)
{
    __shared__ float tile[32][33];
    const int bx = blockIdx.x * 32;  // N offset
    const int by = blockIdx.y * 32;  // K offset
    const int tx = threadIdx.x;      // 0..31
    const int ty = threadIdx.y;      // 0..7
    #pragma unroll
    for (int i = 0; i < 32; i += 8)
        tile[ty + i][tx] = W[(size_t)(by + ty + i) * N + bx + tx];
    __syncthreads();
    #pragma unroll
    for (int i = 0; i < 32; i += 8)
        Wt[(size_t)(bx + ty + i) * K + by + tx] = f2bf(tile[tx][ty + i]);
}

// ---------------------------------------------------------------------------
// Concat bq,bk,bv -> bqkv[3072]
// ---------------------------------------------------------------------------
__global__ void concat_bias_kernel(const float* __restrict__ bq,
                                   const float* __restrict__ bk,
                                   const float* __restrict__ bv,
                                   float* __restrict__ bqkv)
{
    int i = blockIdx.x * blockDim.x + threadIdx.x;
    if (i < 3 * D_) {
        float v = (i < D_) ? bq[i] : (i < 2 * D_) ? bk[i - D_] : bv[i - 2 * D_];
        bqkv[i] = v;
    }
}

// ---------------------------------------------------------------------------
// LayerNorm: fp32 in [rows][1024] -> bf16 out
// ---------------------------------------------------------------------------
__global__ __launch_bounds__(256) void ln_kernel(
    const float* __restrict__ x, const float* __restrict__ g,
    const float* __restrict__ be, ushort_t* __restrict__ out)
{
    const int row = blockIdx.x;
    const int t = threadIdx.x;
    const int lane = t & 63;
    const int wave = t >> 6;
    const float4* xr = (const float4*)(x + (size_t)row * D_);
    float4 v = xr[t];
    float s  = v.x + v.y + v.z + v.w;
    float s2 = v.x * v.x + v.y * v.y + v.z * v.z + v.w * v.w;
    #pragma unroll
    for (int off = 32; off; off >>= 1) {
        s  += __shfl_xor(s, off);
        s2 += __shfl_xor(s2, off);
    }
    __shared__ float red[8];
    if (lane == 0) { red[wave * 2] = s; red[wave * 2 + 1] = s2; }
    __syncthreads();
    s  = red[0] + red[2] + red[4] + red[6];
    s2 = red[1] + red[3] + red[5] + red[7];
    const float mean = s * (1.0f / D_);
    const float var  = s2 * (1.0f / D_) - mean * mean;
    const float rstd = rsqrtf(var + EPS_);
    const float4 gv  = ((const float4*)g)[t];
    const float4 bv  = ((const float4*)be)[t];
    ushort_t o[4];
    o[0] = f2bf((v.x - mean) * rstd * gv.x + bv.x);
    o[1] = f2bf((v.y - mean) * rstd * gv.y + bv.y);
    o[2] = f2bf((v.z - mean) * rstd * gv.z + bv.z);
    o[3] = f2bf((v.w - mean) * rstd * gv.w + bv.w);
    *(ushort2*)&out[(size_t)row * D_ + t * 4]     = make_ushort2(o[0], o[1]);
    *(ushort2*)&out[(size_t)row * D_ + t * 4 + 2] = make_ushort2(o[2], o[3]);
}

// ---------------------------------------------------------------------------
// V transpose: qkv cols 2048.. (bf16 [8192][3072]) -> vt [64 bh][64 hd][2048 s]
// LDS-tiled (swizzled), coalesced read and write.
// ---------------------------------------------------------------------------
__global__ __launch_bounds__(256) void vtrans_kernel(
    const ushort_t* __restrict__ qkv, ushort_t* __restrict__ vt)
{
    __shared__ __align__(16) ushort_t T[256 * 64];   // [s][hd], chunk ^= s&7
    const int tid  = threadIdx.x;
    const int sblk = blockIdx.x & 7;
    const int bh   = blockIdx.x >> 3;
    const int b = bh >> 4, h = bh & 15;
    const ushort_t* src = qkv + (size_t)(b * S_ + sblk * 256) * (3 * D_) + 2 * D_ + h * 64;
    #pragma unroll
    for (int p = 0; p < 8; ++p) {
        const int L = p * 256 + tid;
        const int s = L >> 3, c = L & 7;
        bf16x8 v = *(const bf16x8*)(src + (size_t)s * (3 * D_) + c * 8);
        *(bf16x8*)&T[s * 64 + ((c ^ (s & 7)) << 3)] = v;
    }
    __syncthreads();
    #pragma unroll
    for (int p = 0; p < 8; ++p) {
        const int L = p * 256 + tid;
        const int hd = L >> 5, scn = L & 31;
        ushort_t tmp[8];
        #pragma unroll
        for (int j = 0; j < 8; ++j) {
            const int s = scn * 8 + j;
            tmp[j] = T[s * 64 + (((hd >> 3) ^ (s & 7)) << 3) + (hd & 7)];
        }
        *(bf16x8*)&vt[((size_t)bh * 64 + hd) * S_ + sblk * 256 + scn * 8] =
            *(const bf16x8*)tmp;
    }
}

// ---------------------------------------------------------------------------
// GEMM (R9-verified BM=128 config): C[M][N] = epilogue(A @ Bt^T + bias)
// BM=128, BN=256, BK=32, 8 waves (2M x 4N, 64x64/wave), 512 thr.
// 3-buffer LDS (72KB -> 2 blocks/CU, 16 waves/CU), counted vmcnt(3).
// Swizzle: stored chunk = logical ^ ((row>>1)&3) [verified 0-conflict, R8].
// T1 bijective XCD swizzle (grids % 8 == 0), T5 setprio.
// ---------------------------------------------------------------------------
template <int MODE>
__global__ __launch_bounds__(512, 2) void gemmT_kernel(
    const ushort_t* __restrict__ A, const ushort_t* __restrict__ Bt,
    const float* __restrict__ bias, const float* __restrict__ res,
    void* __restrict__ Cout, int M, int N, int K, int gx)
{
    constexpr int LOADS = 3;               // gloads per K-tile per thread

    __shared__ __align__(16) ushort_t As[3][128 * 32];
    __shared__ __align__(16) ushort_t Bs[3][256 * 32];

    const int tid  = threadIdx.x;
    const int w    = tid >> 6;
    const int lane = tid & 63;
    const int l15  = lane & 15;
    const int g    = lane >> 4;

    const int cpx = gridDim.x >> 3;
    const int swz = (blockIdx.x & 7) * cpx + (blockIdx.x >> 3);
    const int bx = swz % gx, by = swz / gx;
    const int m0 = by * 128, n0 = bx * 256;

    const int wm = (w >> 2) * 64;          // 2 M-waves
    const int wn = (w & 3) * 64;           // 4 N-waves

    const ushort_t* srcA;
    int ldsA;
    const ushort_t* srcB[2];
    int ldsB[2];
    {
        const int L = tid;
        const int row = L >> 2;
        srcA = A + (size_t)(m0 + row) * K + (((L & 3) ^ ((row >> 1) & 3)) << 3);
        ldsA = (w * 64) * 8;
    }
    #pragma unroll
    for (int p = 0; p < 2; ++p) {
        const int L = p * 512 + tid;
        const int row = L >> 2;
        srcB[p] = Bt + (size_t)(n0 + row) * K + (((L & 3) ^ ((row >> 1) & 3)) << 3);
        ldsB[p] = (p * 512 + w * 64) * 8;
    }

    #define STAGE(koff_, buf_)                                               \
        do {                                                                 \
            GLDS(srcA + (koff_), &As[buf_][ldsA]);                           \
            GLDS(srcB[0] + (koff_), &Bs[buf_][ldsB[0]]);                     \
            GLDS(srcB[1] + (koff_), &Bs[buf_][ldsB[1]]);                     \
        } while (0)

    #define LDA(mf_) (*(const bf16x8*)&As[cur][(wm + (mf_) * 16 + l15) * 32 + \
                        ((g ^ (((wm + (mf_) * 16 + l15) >> 1) & 3)) << 3)])
    #define LDB(nf_) (*(const bf16x8*)&Bs[cur][(wn + (nf_) * 16 + l15) * 32 + \
                        ((g ^ (((wn + (nf_) * 16 + l15) >> 1) & 3)) << 3)])

    f32x4 acc[4][4] = {};
    const int NT = K >> 5;

    STAGE(0, 0);
    STAGE(32, 1);
    asm volatile("s_waitcnt vmcnt(%0)" :: "n"(LOADS) : "memory");
    __builtin_amdgcn_s_barrier();

    for (int t = 0; t < NT; ++t) {
        const int cur = t % 3;
        const bool more = (t + 2 < NT);
        const size_t koff = (size_t)(t + 2) * 32;

        bf16x8 af[4], bfr[4];
        #pragma unroll
        for (int nf = 0; nf < 4; ++nf) bfr[nf] = LDB(nf);
        #pragma unroll
        for (int mf = 0; mf < 4; ++mf) af[mf] = LDA(mf);

        if (more) STAGE(koff, (t + 2) % 3);
        __builtin_amdgcn_s_setprio(1);
        #pragma unroll
        for (int mf = 0; mf < 4; ++mf)
            #pragma unroll
            for (int nf = 0; nf < 4; ++nf)
                acc[mf][nf] = __builtin_amdgcn_mfma_f32_16x16x32_bf16(
                    af[mf], bfr[nf], acc[mf][nf], 0, 0, 0);
        __builtin_amdgcn_s_setprio(0);
        if (more)
            asm volatile("s_waitcnt vmcnt(%0)" :: "n"(LOADS) : "memory");
        else
            asm volatile("s_waitcnt vmcnt(0)" ::: "memory");
        __builtin_amdgcn_s_barrier();
    }
    #undef STAGE
    #undef LDA
    #undef LDB

    const int rbase = g * 4;
    #pragma unroll
    for (int mf = 0; mf < 4; ++mf) {
        #pragma unroll
        for (int nf = 0; nf < 4; ++nf) {
            const int col = n0 + wn + nf * 16 + l15;
            const float bcol = bias[col];
            #pragma unroll
            for (int r = 0; r < 4; ++r) {
                const int row = m0 + wm + mf * 16 + rbase + r;
                float v = acc[mf][nf][r] + bcol;
                const size_t idx = (size_t)row * N + col;
                if (MODE == 0) {
                    ((ushort_t*)Cout)[idx] = f2bf(v);
                } else if (MODE == 1) {
                    ((ushort_t*)Cout)[idx] = f2bf(fmaxf(v, 0.0f));
                } else {
                    ((float*)Cout)[idx] = res[idx] + RES_ * v;
                }
            }
        }
    }
}

// ---------------------------------------------------------------------------
// Flash attention v7 (causal, paired-KV). Q,K from packed qkv; V from vt.
// - 64-row q-tiles, 4 waves x 16 rows; paired triangle (33 kv-blocks/block)
// - TWO kv-blocks per loop body: Ks[2]/Vt[2], joint max, one barrier pair
//   and one shfl-reduce pair per 128 keys; only pair-block1 can cross diag.
// - bh-coherent XCD mapping (lin%8 == bh%8); exp2 softmax; defer-max (T13)
// out: bf16 [8192][1024]
// ---------------------------------------------------------------------------
__global__ __launch_bounds__(256) void fattn_kernel(
    const ushort_t* __restrict__ qkv, const ushort_t* __restrict__ vtg,
    ushort_t* __restrict__ out)
{
    __shared__ __align__(16) ushort_t Ks[2][64 * 64];
    __shared__ __align__(16) ushort_t Vt[2][64 * 64];
    __shared__ __align__(16) ushort_t Ps[4][16 * 64];

    const int tid  = threadIdx.x;
    const int lane = tid & 63;
    const int w    = tid >> 6;
    const int lin  = blockIdx.x;
    const int xi   = lin >> 6;          // 0..15
    const int bh   = lin & 63;          // lin%8 == bh%8 -> XCD-coherent
    const int b = bh >> 4, h = bh & 15;

    const int l15 = lane & 15;
    const int g   = lane >> 4;

    const size_t rs = 3 * D_;
    const ushort_t* Qg = qkv + (size_t)b * S_ * rs + h * HD_;
    const ushort_t* Kg = Qg + D_;
    const ushort_t* Vg = vtg + (size_t)bh * HD_ * S_;   // [hd][s]

    const int srow = tid >> 3;          // 0..31 (+32 on pass 1)
    const int sc   = tid & 7;

    #pragma unroll
    for (int half = 0; half < 2; ++half) {
        const int qt = half ? xi : (S_ / 64 - 1) - xi;
        const int q0 = qt * 64;
        const int nkb = qt + 1;

        // Q B-frags, pre-scaled by SCALE_*log2e
        bf16x8 qf[2];
        {
            const int qrow = q0 + w * 16 + l15;
            #pragma unroll
            for (int kk = 0; kk < 2; ++kk) {
                bf16x8 tq = *(const bf16x8*)(Qg + (size_t)qrow * rs + kk * 32 + g * 8);
                #pragma unroll
                for (int e = 0; e < 8; ++e)
                    tq[e] = (short)f2bf(bf2f((ushort_t)tq[e]) * (SCALE_ * LOG2E_));
                qf[kk] = tq;
            }
        }

        float mrow = -1e30f, lrow = 0.f;
        f32x4 oacc[4] = {};

        bf16x8 kvreg[2][2], vvreg[2][2];
        #pragma unroll
        for (int p = 0; p < 2; ++p) {
            const int row = p * 32 + srow;
            kvreg[0][p] = *(const bf16x8*)(Kg + (size_t)row * rs + sc * 8);
            vvreg[0][p] = *(const bf16x8*)(Vg + (size_t)row * S_ + sc * 8);
        }
        if (nkb > 1) {
            #pragma unroll
            for (int p = 0; p < 2; ++p) {
                const int row = p * 32 + srow;
                kvreg[1][p] = *(const bf16x8*)(Kg + (size_t)(64 + row) * rs + sc * 8);
                vvreg[1][p] = *(const bf16x8*)(Vg + (size_t)row * S_ + 64 + sc * 8);
            }
        }

        int kb = 0;
        for (; kb + 1 < nkb; kb += 2) {
            __syncthreads();
            #pragma unroll
            for (int s = 0; s < 2; ++s)
                #pragma unroll
                for (int p = 0; p < 2; ++p) {
                    const int row = p * 32 + srow;
                    *(bf16x8*)&Ks[s][row * 64 + ((sc ^ (row & 7)) << 3)] = kvreg[s][p];
                    *(bf16x8*)&Vt[s][row * 64 + ((sc ^ (row & 7)) << 3)] = vvreg[s][p];
                }
            if (kb + 2 < nkb) {
                #pragma unroll
                for (int p = 0; p < 2; ++p) {
                    const int row = p * 32 + srow;
                    kvreg[0][p] = *(const bf16x8*)(
                        Kg + (size_t)((kb + 2) * 64 + row) * rs + sc * 8);
                    vvreg[0][p] = *(const bf16x8*)(
                        Vg + (size_t)row * S_ + (kb + 2) * 64 + sc * 8);
                }
            }
            if (kb + 3 < nkb) {
                #pragma unroll
                for (int p = 0; p < 2; ++p) {
                    const int row = p * 32 + srow;
                    kvreg[1][p] = *(const bf16x8*)(
                        Kg + (size_t)((kb + 3) * 64 + row) * rs + sc * 8);
                    vvreg[1][p] = *(const bf16x8*)(
                        Vg + (size_t)row * S_ + (kb + 3) * 64 + sc * 8);
                }
            }
            __syncthreads();

            // ---- QK^T for both blocks (independent chains) ----
            f32x4 sf0[4] = {}, sf1[4] = {};
            __builtin_amdgcn_s_setprio(1);
            #pragma unroll
            for (int kk = 0; kk < 2; ++kk) {
                const int cc = kk * 4 + g;
                #pragma unroll
                for (int nf = 0; nf < 4; ++nf) {
                    const int keyr = nf * 16 + l15;
                    const int ko = keyr * 64 + ((cc ^ (keyr & 7)) << 3);
                    bf16x8 kf0 = *(const bf16x8*)&Ks[0][ko];
                    bf16x8 kf1 = *(const bf16x8*)&Ks[1][ko];
                    sf0[nf] = __builtin_amdgcn_mfma_f32_16x16x32_bf16(kf0, qf[kk], sf0[nf], 0, 0, 0);
                    sf1[nf] = __builtin_amdgcn_mfma_f32_16x16x32_bf16(kf1, qf[kk], sf1[nf], 0, 0, 0);
                }
            }
            __builtin_amdgcn_s_setprio(0);

            // only pair-block1 can cross the diagonal
            if (kb + 1 == nkb - 1) {
                const int q = q0 + w * 16 + l15;
                #pragma unroll
                for (int nf = 0; nf < 4; ++nf)
                    #pragma unroll
                    for (int r = 0; r < 4; ++r)
                        if ((kb + 1) * 64 + nf * 16 + g * 4 + r > q) sf1[nf][r] = -1e30f;
            }

            // ---- joint max over 32 scores ----
            float mx = -1e30f;
            #pragma unroll
            for (int nf = 0; nf < 4; ++nf)
                #pragma unroll
                for (int r = 0; r < 4; ++r) {
                    mx = fmaxf(mx, sf0[nf][r]);
                    mx = fmaxf(mx, sf1[nf][r]);
                }
            mx = fmaxf(mx, __shfl_xor(mx, 16));
            mx = fmaxf(mx, __shfl_xor(mx, 32));

            if (!__all(mx - mrow <= 8.0f)) {
                const float mnew = fmaxf(mrow, mx);
                const float corr = fexp2(mrow - mnew);
                mrow = mnew;
                lrow *= corr;
                #pragma unroll
                for (int r = 0; r < 4; ++r) {
                    const float cr = __shfl(corr, g * 4 + r, 16);
                    #pragma unroll
                    for (int nf = 0; nf < 4; ++nf) oacc[nf][r] *= cr;
                }
            }

            // ---- exp, psum, P write + PV for each block ----
            float psum = 0.f;
            const int qrow = l15;
            #pragma unroll
            for (int s = 0; s < 2; ++s) {
                const f32x4* sfp = s ? sf1 : sf0;
                #pragma unroll
                for (int nf = 0; nf < 4; ++nf) {
                    const float p0 = fexp2(sfp[nf][0] - mrow);
                    const float p1 = fexp2(sfp[nf][1] - mrow);
                    const float p2 = fexp2(sfp[nf][2] - mrow);
                    const float p3 = fexp2(sfp[nf][3] - mrow);
                    psum += (p0 + p1) + (p2 + p3);
                    uint2 pk = make_uint2(cvt_pk_bf16(p0, p1), cvt_pk_bf16(p2, p3));
                    const int c16 = ((nf << 1) + (g >> 1)) ^ (qrow & 7);
                    *(uint2*)((char*)Ps[w] + qrow * 128 + c16 * 16 + (g & 1) * 8) = pk;
                }
                #pragma unroll
                for (int kk = 0; kk < 2; ++kk) {
                    const int cc = kk * 4 + g;
                    const int c16 = cc ^ (qrow & 7);
                    bf16x8 pa = *(const bf16x8*)((const char*)Ps[w] + qrow * 128 + c16 * 16);
                    __builtin_amdgcn_s_setprio(1);
                    #pragma unroll
                    for (int nf = 0; nf < 4; ++nf) {
                        const int dr = nf * 16 + l15;
                        bf16x8 vf = *(const bf16x8*)&Vt[s][dr * 64 + ((cc ^ (dr & 7)) << 3)];
                        oacc[nf] = __builtin_amdgcn_mfma_f32_16x16x32_bf16(pa, vf, oacc[nf], 0, 0, 0);
                    }
                    __builtin_amdgcn_s_setprio(0);
                }
            }
            psum += __shfl_xor(psum, 16);
            psum += __shfl_xor(psum, 32);
            lrow += psum;
        }

        // ---- tail single block (set 0 holds it; always the diagonal block) ----
        if (kb < nkb) {
            __syncthreads();
            #pragma unroll
            for (int p = 0; p < 2; ++p) {
                const int row = p * 32 + srow;
                *(bf16x8*)&Ks[0][row * 64 + ((sc ^ (row & 7)) << 3)] = kvreg[0][p];
                *(bf16x8*)&Vt[0][row * 64 + ((sc ^ (row & 7)) << 3)] = vvreg[0][p];
            }
            __syncthreads();

            f32x4 sf0[4] = {};
            __builtin_amdgcn_s_setprio(1);
            #pragma unroll
            for (int kk = 0; kk < 2; ++kk) {
                const int cc = kk * 4 + g;
                #pragma unroll
                for (int nf = 0; nf < 4; ++nf) {
                    const int keyr = nf * 16 + l15;
                    bf16x8 kf = *(const bf16x8*)&Ks[0][keyr * 64 + ((cc ^ (keyr & 7)) << 3)];
                    sf0[nf] = __builtin_amdgcn_mfma_f32_16x16x32_bf16(kf, qf[kk], sf0[nf], 0, 0, 0);
                }
            }
            __builtin_amdgcn_s_setprio(0);

            {
                const int q = q0 + w * 16 + l15;
                #pragma unroll
                for (int nf = 0; nf < 4; ++nf)
                    #pragma unroll
                    for (int r = 0; r < 4; ++r)
                        if (kb * 64 + nf * 16 + g * 4 + r > q) sf0[nf][r] = -1e30f;
            }
            float mx = -1e30f;
            #pragma unroll
            for (int nf = 0; nf < 4; ++nf)
                #pragma unroll
                for (int r = 0; r < 4; ++r) mx = fmaxf(mx, sf0[nf][r]);
            mx = fmaxf(mx, __shfl_xor(mx, 16));
            mx = fmaxf(mx, __shfl_xor(mx, 32));

            if (!__all(mx - mrow <= 8.0f)) {
                const float mnew = fmaxf(mrow, mx);
                const float corr = fexp2(mrow - mnew);
                mrow = mnew;
                lrow *= corr;
                #pragma unroll
                for (int r = 0; r < 4; ++r) {
                    const float cr = __shfl(corr, g * 4 + r, 16);
                    #pragma unroll
                    for (int nf = 0; nf < 4; ++nf) oacc[nf][r] *= cr;
                }
            }

            float psum = 0.f;
            const int qrow = l15;
            #pragma unroll
            for (int nf = 0; nf < 4; ++nf) {
                const float p0 = fexp2(sf0[nf][0] - mrow);
                const float p1 = fexp2(sf0[nf][1] - mrow);
                const float p2 = fexp2(sf0[nf][2] - mrow);
                const float p3 = fexp2(sf0[nf][3] - mrow);
                psum += (p0 + p1) + (p2 + p3);
                uint2 pk = make_uint2(cvt_pk_bf16(p0, p1), cvt_pk_bf16(p2, p3));
                const int c16 = ((nf << 1) + (g >> 1)) ^ (qrow & 7);
                *(uint2*)((char*)Ps[w] + qrow * 128 + c16 * 16 + (g & 1) * 8) = pk;
            }
            psum += __shfl_xor(psum, 16);
            psum += __shfl_xor(psum, 32);
            lrow += psum;

            #pragma unroll
            for (int kk = 0; kk < 2; ++kk) {
                const int cc = kk * 4 + g;
                const int c16 = cc ^ (qrow & 7);
                bf16x8 pa = *(const bf16x8*)((const char*)Ps[w] + qrow * 128 + c16 * 16);
                __builtin_amdgcn_s_setprio(1);
                #pragma unroll
                for (int nf = 0; nf < 4; ++nf) {
                    const int dr = nf * 16 + l15;
                    bf16x8 vf = *(const bf16x8*)&Vt[0][dr * 64 + ((cc ^ (dr & 7)) << 3)];
                    oacc[nf] = __builtin_amdgcn_mfma_f32_16x16x32_bf16(pa, vf, oacc[nf], 0, 0, 0);
                }
                __builtin_amdgcn_s_setprio(0);
            }
        }

        // ---- epilogue: O = acc / l ----
        const float linv = 1.0f / lrow;
        #pragma unroll
        for (int r = 0; r < 4; ++r) {
            const float li = __shfl(linv, g * 4 + r, 16);
            const int q = q0 + w * 16 + g * 4 + r;
            ushort_t* op = out + (size_t)(b * S_ + q) * D_ + h * HD_;
            #pragma unroll
            for (int nf = 0; nf < 4; ++nf)
                op[nf * 16 + l15] = f2bf(oacc[nf][r] * li);
        }
    }
}

// ---------------------------------------------------------------------------
// launch
// ---------------------------------------------------------------------------
extern "C" void kernel_launch(void* const* d_in, const int* in_sizes, int n_in,
                              void* d_out, int out_size, void* d_ws, size_t ws_size,
                              hipStream_t stream)
{
    const float* x   = (const float*)d_in[0];
    const float* Wq  = (const float*)d_in[1];
    const float* bq  = (const float*)d_in[2];
    const float* Wk  = (const float*)d_in[3];
    const float* bk  = (const float*)d_in[4];
    const float* Wv  = (const float*)d_in[5];
    const float* bv  = (const float*)d_in[6];
    const float* Wo  = (const float*)d_in[7];
    const float* bo  = (const float*)d_in[8];
    const float* g1  = (const float*)d_in[9];
    const float* be1 = (const float*)d_in[10];
    const float* g2  = (const float*)d_in[11];
    const float* be2 = (const float*)d_in[12];
    const float* W1  = (const float*)d_in[13];
    const float* b1  = (const float*)d_in[14];
    const float* W2  = (const float*)d_in[15];
    const float* b2  = (const float*)d_in[16];
    float* out = (float*)d_out;

    char* ws = (char*)d_ws;
    size_t o = 0;
    auto alloc = [&](size_t bytes) { size_t r = o; o = (o + bytes + 255) & ~(size_t)255; return r; };
    ushort_t* Wqkvt = (ushort_t*)(ws + alloc((size_t)3 * D_ * D_ * 2));   // [3072][1024]
    ushort_t* Wot   = (ushort_t*)(ws + alloc((size_t)D_ * D_ * 2));      // [1024][1024]
    ushort_t* W1t   = (ushort_t*)(ws + alloc((size_t)DFF_ * D_ * 2));    // [4096][1024]
    ushort_t* W2t   = (ushort_t*)(ws + alloc((size_t)D_ * DFF_ * 2));    // [1024][4096]
    float*    bqkv  = (float*)(ws + alloc((size_t)3 * D_ * 4));
    ushort_t* lnbuf = (ushort_t*)(ws + alloc((size_t)M_ * D_ * 2));      // ln1 then ln2
    ushort_t* bigbuf= (ushort_t*)(ws + alloc((size_t)M_ * DFF_ * 2));    // qkv then ffn-hidden
    ushort_t* attnb = (ushort_t*)(ws + alloc((size_t)M_ * D_ * 2));
    float*    x1    = (float*)(ws + alloc((size_t)M_ * D_ * 4));
    ushort_t* vtbuf = (ushort_t*)(ws + alloc((size_t)M_ * D_ * 2));      // V^T [bh][hd][s]

    dim3 tblock(32, 8);
    transpose_cast_kernel<<<dim3(D_/32, D_/32), tblock, 0, stream>>>(Wq, Wqkvt,            D_, D_);
    transpose_cast_kernel<<<dim3(D_/32, D_/32), tblock, 0, stream>>>(Wk, Wqkvt + D_*D_,    D_, D_);
    transpose_cast_kernel<<<dim3(D_/32, D_/32), tblock, 0, stream>>>(Wv, Wqkvt + 2*D_*D_,  D_, D_);
    transpose_cast_kernel<<<dim3(D_/32, D_/32), tblock, 0, stream>>>(Wo, Wot,              D_, D_);
    transpose_cast_kernel<<<dim3(DFF_/32, D_/32), tblock, 0, stream>>>(W1, W1t,            D_, DFF_);
    transpose_cast_kernel<<<dim3(D_/32, DFF_/32), tblock, 0, stream>>>(W2, W2t,            DFF_, D_);
    concat_bias_kernel<<<12, 256, 0, stream>>>(bq, bk, bv, bqkv);

    // ln1
    ln_kernel<<<M_, 256, 0, stream>>>(x, g1, be1, lnbuf);
    // qkv = ln1 @ Wqkv + bqkv          [8192][3072] bf16   grid 64*12=768
    gemmT_kernel<0><<<(M_/128)*(3*D_/256), 512, 0, stream>>>(
        lnbuf, Wqkvt, bqkv, nullptr, bigbuf, M_, 3*D_, D_, 3*D_/256);
    // V transpose -> vtbuf [bh][hd][s]  grid 512
    vtrans_kernel<<<512, 256, 0, stream>>>(bigbuf, vtbuf);
    // flash attention (paired q-tiles + paired KV)  [8192][1024] bf16
    fattn_kernel<<<(S_/128) * 64, 256, 0, stream>>>(bigbuf, vtbuf, attnb);
    // x1 = x + RES*(attn @ Wo + bo)     [8192][1024] fp32  grid 64*4=256
    gemmT_kernel<2><<<(M_/128)*(D_/256), 512, 0, stream>>>(
        attnb, Wot, bo, x, x1, M_, D_, D_, D_/256);
    // ln2
    ln_kernel<<<M_, 256, 0, stream>>>(x1, g2, be2, lnbuf);
    // ffh = relu(ln2 @ W1 + b1)         [8192][4096] bf16  grid 64*16=1024
    gemmT_kernel<1><<<(M_/128)*(DFF_/256), 512, 0, stream>>>(
        lnbuf, W1t, b1, nullptr, bigbuf, M_, DFF_, D_, DFF_/256);
    // out = x1 + RES*(ffh @ W2 + b2)    [8192][1024] fp32  grid 64*4=256
    gemmT_kernel<2><<<(M_/128)*(D_/256), 512, 0, stream>>>(
        bigbuf, W2t, b2, x1, out, M_, D_, DFF_, D_/256);
}